// Round 13
// baseline (529.200 us; speedup 1.0000x reference)
//
#include <hip/hip_runtime.h>
#include <hip/hip_bf16.h>

#define NLOC_   4096
#define NALL_   6144
#define NEDGE_  262144
#define NANGLE_ 409600

typedef __bf16 bf16x8 __attribute__((ext_vector_type(8)));
typedef float  f32x4  __attribute__((ext_vector_type(4)));
typedef unsigned short u16;

__device__ __forceinline__ float silu_(float x){ return x / (1.0f + __expf(-x)); }

__device__ __forceinline__ u16 f2bu(float f){
    union { float f; unsigned u; } v; v.f = f;
    unsigned r = v.u + 0x7fffu + ((v.u >> 16) & 1u);
    return (u16)(r >> 16);
}
__device__ __forceinline__ float bu2f(u16 b){
    union { unsigned u; float f; } v; v.u = ((unsigned)b) << 16; return v.f;
}
__device__ __forceinline__ void st_bf16x4(u16* dst, float4 v){
    unsigned lo = (unsigned)f2bu(v.x) | ((unsigned)f2bu(v.y) << 16);
    unsigned hi = (unsigned)f2bu(v.z) | ((unsigned)f2bu(v.w) << 16);
    *reinterpret_cast<uint2*>(dst) = make_uint2(lo, hi);
}

// ---------------------------------------------------------------------------
// L1 mega-prep: weight transposes + bf16 tables + CSR counts, block-ranged.
// ---------------------------------------------------------------------------
__global__ __launch_bounds__(256) void k_mega_prep(
    const float* __restrict__ Wne, const float* __restrict__ Wes,
    const float* __restrict__ W1,  const float* __restrict__ WA,
    const float* __restrict__ W2,  const float* __restrict__ Wsym,
    const float* __restrict__ Wns,
    const float* __restrict__ node_ext, const float* __restrict__ edge_ebd,
    const int* __restrict__ n2e, const int* __restrict__ eij2a,
    u16* __restrict__ WTe, u16* __restrict__ WTa2, u16* __restrict__ WTaN,
    u16* __restrict__ WT2, u16* __restrict__ WsymT, u16* __restrict__ WnsT,
    u16* __restrict__ NB, u16* __restrict__ EB,
    int* __restrict__ cnt, int* __restrict__ cnt2)
{
    const int b = blockIdx.x, tid = threadIdx.x;
    if (b < 812) {
        int i = b*256 + tid;
        if (i < 61440) {                       // WTe[192][320]
            int r = i/320, c = i - r*320;
            WTe[i] = f2bu(r < 128 ? Wne[c*128 + r] : Wes[c*64 + (r-128)]);
        } else if (i < 76800) {                // WTa2[96][160]
            int j = i - 61440; int r = j/160, c2 = j - r*160;
            int k = (c2 < 32) ? c2 : c2 + 128;
            WTa2[j] = f2bu(r < 64 ? W1[k*64 + r] : WA[k*32 + (r-64)]);
        } else if (i < 89088) {                // WTaN[96][128]
            int j = i - 76800; int r = j >> 7, c2 = j & 127;
            int k = c2 + 32;
            WTaN[j] = f2bu(r < 64 ? W1[k*64 + r] : WA[k*32 + (r-64)]);
        } else if (i < 93184) {                // WT2[64][64]
            int j = i - 89088; int r = j >> 6, c = j & 63;
            WT2[j] = f2bu(W2[c*64 + r]);
        } else if (i < 191488) {               // WsymT[128][768]
            int j = i - 93184; int r = j/768, c = j - r*768;
            WsymT[j] = f2bu(Wsym[c*128 + r]);
        } else {                               // WnsT[128][128]
            int j = i - 191488; int r = j >> 7, c = j & 127;
            WnsT[j] = f2bu(Wns[c*128 + r]);
        }
    } else if (b < 1580) {                     // NB
        int i = (b - 812)*256 + tid;
        float4 v = ((const float4*)node_ext)[i];
        st_bf16x4(&NB[(size_t)i*4], v);
    } else if (b < 3628) {                     // EB
        for (int i = (b - 1580)*256 + tid; i < NEDGE_*64/4; i += 2048*256) {
            float4 v = ((const float4*)edge_ebd)[i];
            st_bf16x4(&EB[(size_t)i*4], v);
        }
    } else if (b < 4652) {                     // count n2e
        int e = (b - 3628)*256 + tid;
        atomicAdd(&cnt[n2e[e]], 1);
    } else {                                   // count eij2a
        int a = (b - 4652)*256 + tid;
        atomicAdd(&cnt2[eij2a[a]], 1);
    }
}

// ---------------------------------------------------------------------------
// L2: block 0 = node scan; 1..256 = scan2a; 257..320 = nconst; 321..384 = nconstA.
// ---------------------------------------------------------------------------
__global__ __launch_bounds__(256) void k_scan_misc(
    const int* __restrict__ cnt, int* __restrict__ off, int* __restrict__ cursor,
    const int* __restrict__ cnt2, int* __restrict__ bsum,
    const u16* __restrict__ NB, const u16* __restrict__ WTe,
    const u16* __restrict__ WTaN,
    float* __restrict__ nconst, float* __restrict__ nconstA)
{
    __shared__ __align__(16) u16 sN[64][136];
    int* wa = (int*)&sN[0][0];
    const int b = blockIdx.x, t = threadIdx.x;

    if (b == 0) {
        int v[16]; int s = 0;
        #pragma unroll
        for (int k = 0; k < 16; ++k) { v[k] = s; s += cnt[16*t + k]; }
        wa[t] = s;
        __syncthreads();
        for (int d = 1; d < 256; d <<= 1) {
            int x = wa[t];
            int y = (t >= d) ? wa[t-d] : 0;
            __syncthreads();
            wa[t] = x + y;
            __syncthreads();
        }
        int excl = (t == 0) ? 0 : wa[t-1];
        #pragma unroll
        for (int k = 0; k < 16; ++k) {
            off[16*t + k]    = excl + v[k];
            cursor[16*t + k] = excl + v[k];
        }
        if (t == 255) off[4096] = excl + s;
    } else if (b <= 256) {
        int bb = b - 1;
        int4 v = ((const int4*)cnt2)[bb*256 + t];
        wa[t] = v.x + v.y + v.z + v.w;
        __syncthreads();
        for (int d = 128; d > 0; d >>= 1) {
            if (t < d) wa[t] += wa[t+d];
            __syncthreads();
        }
        if (t == 0) bsum[bb] = wa[0];
    } else if (b <= 320) {
        const int e0 = (b - 257) * 64;
        #pragma unroll
        for (int f = t; f < 1024; f += 256) {
            int r = f >> 4, c = f & 15;
            *(uint4*)&sN[r][8*c] = ((const uint4*)&NB[(size_t)(e0 + r)*128])[c];
        }
        __syncthreads();
        const int w = t >> 6, l = t & 63;
        const int lr = l & 15, hq = l >> 4, lk = hq * 8;
        f32x4 acc[4][3] = {};
        #pragma unroll
        for (int kk = 0; kk < 4; ++kk) {
            bf16x8 a[4], bb[3];
            #pragma unroll
            for (int m = 0; m < 4; ++m)
                a[m] = *(const bf16x8*)&sN[16*m + lr][kk*32 + lk];
            #pragma unroll
            for (int nf = 0; nf < 3; ++nf)
                bb[nf] = *(const bf16x8*)&WTe[(size_t)(48*w + 16*nf + lr)*320 + kk*32 + lk];
            #pragma unroll
            for (int m = 0; m < 4; ++m)
                #pragma unroll
                for (int nf = 0; nf < 3; ++nf)
                    acc[m][nf] = __builtin_amdgcn_mfma_f32_16x16x32_bf16(a[m], bb[nf], acc[m][nf], 0, 0, 0);
        }
        #pragma unroll
        for (int nf = 0; nf < 3; ++nf) {
            int c = 48*w + 16*nf + lr;
            #pragma unroll
            for (int m = 0; m < 4; ++m)
                #pragma unroll
                for (int j = 0; j < 4; ++j) {
                    int r = 16*m + 4*hq + j;
                    nconst[(size_t)(e0 + r)*192 + c] = acc[m][nf][j];
                }
        }
    } else {
        const int n0 = (b - 321) * 64;
        #pragma unroll
        for (int f = t; f < 1024; f += 256) {
            int r = f >> 4, c = f & 15;
            *(uint4*)&sN[r][8*c] = ((const uint4*)&NB[(size_t)(n0 + r)*128])[c];
        }
        __syncthreads();
        const int w = t >> 6, l = t & 63;
        const int lr = l & 15, hq = l >> 4, lk = hq * 8;
        f32x4 acc[6] = {};
        #pragma unroll
        for (int kk = 0; kk < 4; ++kk) {
            bf16x8 a = *(const bf16x8*)&sN[16*w + lr][kk*32 + lk];
            #pragma unroll
            for (int nf = 0; nf < 6; ++nf) {
                bf16x8 bb = *(const bf16x8*)&WTaN[(size_t)(16*nf + lr)*128 + kk*32 + lk];
                acc[nf] = __builtin_amdgcn_mfma_f32_16x16x32_bf16(a, bb, acc[nf], 0, 0, 0);
            }
        }
        #pragma unroll
        for (int nf = 0; nf < 6; ++nf) {
            int c = 16*nf + lr;
            #pragma unroll
            for (int j = 0; j < 4; ++j) {
                int r = 16*w + 4*hq + j;
                nconstA[(size_t)(n0 + r)*96 + c] = acc[nf][j];
            }
        }
    }
}

__global__ void k_scan2b(const int* __restrict__ bsum, int* __restrict__ boff)
{
    __shared__ int wa[256];
    int t = threadIdx.x;
    wa[t] = bsum[t];
    __syncthreads();
    for (int d = 1; d < 256; d <<= 1) {
        int x = wa[t];
        int y = (t >= d) ? wa[t-d] : 0;
        __syncthreads();
        wa[t] = x + y;
        __syncthreads();
    }
    boff[t] = (t == 0) ? 0 : wa[t-1];
}

__global__ void k_scan2c(const int* __restrict__ cnt2, const int* __restrict__ boff,
                         int* __restrict__ off2, int* __restrict__ cursor2)
{
    __shared__ int wa[256];
    int b = blockIdx.x, t = threadIdx.x;
    int4 v = ((const int4*)cnt2)[b*256 + t];
    int s1 = v.x, s2 = s1 + v.y, s3 = s2 + v.z, s4 = s3 + v.w;
    wa[t] = s4;
    __syncthreads();
    for (int d = 1; d < 256; d <<= 1) {
        int x = wa[t];
        int y = (t >= d) ? wa[t-d] : 0;
        __syncthreads();
        wa[t] = x + y;
        __syncthreads();
    }
    int base = boff[b] + ((t == 0) ? 0 : wa[t-1]);
    int i = (b*256 + t)*4;
    off2[i]   = base;      cursor2[i]   = base;
    off2[i+1] = base + s1; cursor2[i+1] = base + s1;
    off2[i+2] = base + s2; cursor2[i+2] = base + s2;
    off2[i+3] = base + s3; cursor2[i+3] = base + s3;
    if (b == 255 && t == 255) off2[NEDGE_] = NANGLE_;
}

// L5: fused fills. [0,1024) edge csr; [1024,2624) angle csr2 (sorted list).
__global__ void k_fill2(const int* __restrict__ n2e, int* __restrict__ cursor,
                        int* __restrict__ csr,
                        const int* __restrict__ eij2a, int* __restrict__ cursor2,
                        int* __restrict__ csr2)
{
    int b = blockIdx.x;
    if (b < 1024) {
        int e = b*256 + threadIdx.x;
        int pos = atomicAdd(&cursor[n2e[e]], 1);
        csr[pos] = e;
    } else {
        int a = (b - 1024)*256 + threadIdx.x;
        int pos = atomicAdd(&cursor2[eij2a[a]], 1);
        csr2[pos] = a;
    }
}

// ---------------------------------------------------------------------------
// FUSED edge GEMM + angle GEMM: interleaved block mapping so latency-bound
// edge blocks and angle blocks co-reside on each CU.
//   b<16384: (b&3)==0 -> edge tile b/4 ; else -> angle tile b-(b>>2)-1
//   b>=16384: angle tile 12288+(b-16384)
// ---------------------------------------------------------------------------
__global__ __launch_bounds__(256, 4) void k_edge_angle(
    // edge args
    const u16* __restrict__ NB, const u16* __restrict__ EB,
    const float* __restrict__ h2, const float* __restrict__ sw,
    const int* __restrict__ n2e, const int* __restrict__ n_ext2e,
    const int* __restrict__ csr,
    const u16* __restrict__ WTe, const float* __restrict__ nconst,
    const float* __restrict__ bne, const float* __restrict__ bes,
    float* __restrict__ msg,
    float* __restrict__ h2g2_e, float* __restrict__ h2g2_n,
    u16* __restrict__ eselfO,
    // angle args
    const float* __restrict__ angle_ebd, const float* __restrict__ a_sw,
    const int* __restrict__ n2a, const int* __restrict__ eij2a,
    const int* __restrict__ eik2a, const int* __restrict__ csr2,
    const u16* __restrict__ WTa2, const float* __restrict__ nconstA,
    const float* __restrict__ b1, const float* __restrict__ bA,
    const float* __restrict__ a_res0,
    u16* __restrict__ ea, float* __restrict__ a_out)
{
    __shared__ __align__(16) u16 sA[64][200];
    __shared__ __align__(16) float sH[4][576];
    __shared__ int   s_eid[64];
    __shared__ int   s_node[64];
    __shared__ int   s_g[64];
    __shared__ float s_sw[64];
    __shared__ float s_h2[64][3];
    __shared__ int   s_segstart[65];
    __shared__ int   s_nseg;
    __shared__ int   s_a[32], s_nd[32], s_ij[32], s_ik[32];
    __shared__ float s_asw[32];

    const int tid = threadIdx.x;
    const int b = blockIdx.x;
    bool isEdge; int widx;
    if (b < 16384) {
        if ((b & 3) == 0) { isEdge = true;  widx = b >> 2; }
        else              { isEdge = false; widx = b - (b >> 2) - 1; }
    } else { isEdge = false; widx = 12288 + (b - 16384); }

    const int w  = tid >> 6, l = tid & 63;
    const int lr = l & 15, hq = l >> 4, lk = hq * 8;

    if (isEdge) {
        const int base = widx * 64;

        if (tid < 64) {
            int e = csr[base + tid];
            s_eid[tid]  = e;
            s_node[tid] = n2e[e];
            s_g[tid]    = n_ext2e[e];
            s_sw[tid]   = sw[e];
            s_h2[tid][0] = h2[e*3];
            s_h2[tid][1] = h2[e*3+1];
            s_h2[tid][2] = h2[e*3+2];
        }
        __syncthreads();

        if (tid < 64) {
            bool flag = (tid == 0) || (s_node[tid] != s_node[tid-1]);
            unsigned long long mask = __ballot(flag);
            if (flag) {
                int sid = __popcll(mask & ((1ull << tid) - 1ull));
                s_segstart[sid] = tid;
            }
            if (tid == 0) {
                int ns = __popcll(mask);
                s_nseg = ns;
                s_segstart[ns] = 64;
            }
        }

        #pragma unroll
        for (int f = tid; f < 1024; f += 256) {
            int r = f >> 4, c = f & 15;
            *(uint4*)&sA[r][8*c] = ((const uint4*)&NB[(size_t)s_g[r]*128])[c];
        }
        #pragma unroll
        for (int f = tid; f < 512; f += 256) {
            int r = f >> 3, c = f & 7;
            *(uint4*)&sA[r][128 + 8*c] = ((const uint4*)&EB[(size_t)s_eid[r]*64])[c];
        }
        __syncthreads();

        float bias[3];
        int   cful[3];
        #pragma unroll
        for (int nf = 0; nf < 3; ++nf) {
            int c = 48*w + 16*nf + lr;
            cful[nf] = c;
            bias[nf] = (c < 128) ? bne[c] : bes[c-128];
        }

        f32x4 acc[4][3] = {};
        #pragma unroll
        for (int kk = 0; kk < 6; ++kk) {
            bf16x8 a[4], bb[3];
            #pragma unroll
            for (int m = 0; m < 4; ++m)
                a[m] = *(const bf16x8*)&sA[16*m + lr][kk*32 + lk];
            #pragma unroll
            for (int nf = 0; nf < 3; ++nf)
                bb[nf] = *(const bf16x8*)&WTe[(size_t)cful[nf]*320 + 128 + kk*32 + lk];
            #pragma unroll
            for (int m = 0; m < 4; ++m)
                #pragma unroll
                for (int nf = 0; nf < 3; ++nf)
                    acc[m][nf] = __builtin_amdgcn_mfma_f32_16x16x32_bf16(a[m], bb[nf], acc[m][nf], 0, 0, 0);
        }

        #pragma unroll
        for (int nf = 0; nf < 3; ++nf) {
            int c = cful[nf];
            if (c < 128) {
                #pragma unroll
                for (int m = 0; m < 4; ++m)
                    #pragma unroll
                    for (int j = 0; j < 4; ++j) {
                        int r = 16*m + 4*hq + j;
                        float ncv = nconst[(size_t)s_node[r]*192 + c];
                        acc[m][nf][j] = silu_(acc[m][nf][j] + ncv + bias[nf]) * s_sw[r];
                    }
            } else {
                int c2 = c - 128;
                #pragma unroll
                for (int m = 0; m < 4; ++m)
                    #pragma unroll
                    for (int j = 0; j < 4; ++j) {
                        int r = 16*m + 4*hq + j;
                        float ncv = nconst[(size_t)s_node[r]*192 + c];
                        eselfO[(size_t)s_eid[r]*64 + c2] =
                            f2bu(silu_(acc[m][nf][j] + ncv + bias[nf]));
                    }
            }
        }

        // ---- segmented msg reduction ----
        const int nseg = s_nseg;
        for (int s = 0; s < nseg; ++s) {
            int rs = s_segstart[s], re = s_segstart[s+1];
            int nd = s_node[rs];
            #pragma unroll
            for (int nf = 0; nf < 3; ++nf) {
                if (cful[nf] >= 128) continue;
                float v = 0.f;
                #pragma unroll
                for (int m = 0; m < 4; ++m)
                    #pragma unroll
                    for (int j = 0; j < 4; ++j) {
                        int r = 16*m + 4*hq + j;
                        v += (r >= rs && r < re) ? acc[m][nf][j] : 0.f;
                    }
                v += __shfl_xor(v, 16);
                v += __shfl_xor(v, 32);
                if (hq == 0) atomicAdd(&msg[(size_t)nd*128 + cful[nf]], v);
            }
        }

        // ---- segmented h2g2 accumulation ----
        for (int s = 0; s < nseg; ++s) {
            int rs = s_segstart[s], re = s_segstart[s+1];
            int nd = s_node[rs];
            int lo = max(16*w, rs), hi = min(16*w + 16, re);
            float hacc[9] = {0.f,0.f,0.f,0.f,0.f,0.f,0.f,0.f,0.f};
            for (int r = lo; r < hi; ++r) {
                float swv = s_sw[r];
                float s0 = s_h2[r][0] * swv;
                float s1 = s_h2[r][1] * swv;
                float s2 = s_h2[r][2] * swv;
                float eb = bu2f(sA[r][128 + l]);
                float n0 = bu2f(sA[r][l]);
                float n1 = bu2f(sA[r][64 + l]);
                hacc[0] = fmaf(s0, eb, hacc[0]);
                hacc[1] = fmaf(s1, eb, hacc[1]);
                hacc[2] = fmaf(s2, eb, hacc[2]);
                hacc[3] = fmaf(s0, n0, hacc[3]);
                hacc[4] = fmaf(s0, n1, hacc[4]);
                hacc[5] = fmaf(s1, n0, hacc[5]);
                hacc[6] = fmaf(s1, n1, hacc[6]);
                hacc[7] = fmaf(s2, n0, hacc[7]);
                hacc[8] = fmaf(s2, n1, hacc[8]);
            }
            #pragma unroll
            for (int q = 0; q < 3; ++q) sH[w][q*64 + l] = hacc[q];
            #pragma unroll
            for (int q = 0; q < 6; ++q) sH[w][192 + q*64 + l] = hacc[3+q];
            __syncthreads();
            for (int i = tid; i < 576; i += 256) {
                float v = sH[0][i] + sH[1][i] + sH[2][i] + sH[3][i];
                if (i < 192) atomicAdd(&h2g2_e[(size_t)nd*192 + i], v);
                else         atomicAdd(&h2g2_n[(size_t)nd*384 + (i - 192)], v);
            }
            __syncthreads();
        }
    } else {
        // ---------------- angle path (LDS aliases: sA32 on sA, sEA on sH) ----
        u16 (*sA32)[168] = (u16(*)[168])&sA[0][0];
        u16 (*sEA)[64]   = (u16(*)[64])&sH[0][0];
        const int p0 = widx * 32;

        if (tid < 32) {
            int a = csr2[p0 + tid];
            s_a[tid]  = a;
            s_nd[tid] = n2a[a];
            s_ij[tid] = eij2a[a];
            s_ik[tid] = eik2a[a];
            s_asw[tid] = a_sw[a];
        }
        __syncthreads();

        {                                            // angle_ebd f32 gather
            int r = tid >> 3, c = tid & 7;
            st_bf16x4(&sA32[r][4*c], ((const float4*)angle_ebd)[(size_t)s_a[r]*8 + c]);
        }
        {
            int r = tid >> 3, c = tid & 7;
            *(uint4*)&sA32[r][32 + 8*c] = ((const uint4*)&EB[(size_t)s_ik[r]*64])[c];
            *(uint4*)&sA32[r][96 + 8*c] = ((const uint4*)&EB[(size_t)s_ij[r]*64])[c];
        }
        __syncthreads();

        const int mrow  = (w & 1) * 16;
        const int nbase = (w >> 1) * 48;

        f32x4 acc[3] = {};
        #pragma unroll
        for (int kk = 0; kk < 5; ++kk) {
            bf16x8 a = *(const bf16x8*)&sA32[mrow + lr][kk*32 + lk];
            #pragma unroll
            for (int nf = 0; nf < 3; ++nf) {
                bf16x8 bb = *(const bf16x8*)&WTa2[(size_t)(nbase + 16*nf + lr)*160 + kk*32 + lk];
                acc[nf] = __builtin_amdgcn_mfma_f32_16x16x32_bf16(a, bb, acc[nf], 0, 0, 0);
            }
        }

        #pragma unroll
        for (int nf = 0; nf < 3; ++nf) {
            int c = nbase + 16*nf + lr;
            if (c < 64) {
                float bb = b1[c];
                #pragma unroll
                for (int j = 0; j < 4; ++j) {
                    int r = mrow + 4*hq + j;
                    float nca = nconstA[(size_t)s_nd[r]*96 + c];
                    sEA[r][c] = f2bu(silu_(acc[nf][j] + nca + bb) * s_asw[r]);
                }
            } else {
                int c2 = c - 64;
                float bb = bA[c2], rr = a_res0[c2];
                #pragma unroll
                for (int j = 0; j < 4; ++j) {
                    int r = mrow + 4*hq + j;
                    float nca = nconstA[(size_t)s_nd[r]*96 + c];
                    a_out[(size_t)s_a[r]*32 + c2] =
                        bu2f(sA32[r][c2]) + rr * silu_(acc[nf][j] + nca + bb);
                }
            }
        }
        __syncthreads();

        {                                            // sequential ea store
            int r = tid >> 3, c = tid & 7;
            *(uint4*)&ea[((size_t)(p0 + r))*64 + 8*c] = *(const uint4*)&sEA[r][8*c];
        }
    }
}

// ---------------------------------------------------------------------------
// L8 fused: [0,4096) edgefin; [4096,8192) symc.
// ---------------------------------------------------------------------------
__global__ __launch_bounds__(256) void k_fin(
    const u16* __restrict__ EB, const u16* __restrict__ eselfO,
    const u16* __restrict__ ea, const int* __restrict__ off2,
    const u16* __restrict__ WT2,
    const float* __restrict__ b2_, const float* __restrict__ er0,
    const float* __restrict__ er1,
    float* __restrict__ e_out,
    const float* __restrict__ h2g2_e, const float* __restrict__ h2g2_n,
    u16* __restrict__ symcB)
{
    __shared__ __align__(16) u16 sR[64][72];
    __shared__ __align__(16) u16 sE[64][72];
    __shared__ __align__(16) u16 sB[64][72];
    const int tid = threadIdx.x;
    const int blk = blockIdx.x;

    if (blk < 4096) {
        const int e0 = blk * 64;
        const int w = tid >> 6, l = tid & 63;

        #pragma unroll
        for (int f = tid; f < 512; f += 256) {
            int r = f >> 3, c = f & 7;
            *(uint4*)&sB[r][8*c] = ((const uint4*)&EB[(size_t)(e0 + r)*64])[c];
            *(uint4*)&sE[r][8*c] = ((const uint4*)&eselfO[(size_t)(e0 + r)*64])[c];
        }

        #pragma unroll
        for (int r16 = 0; r16 < 16; ++r16) {
            int r = w*16 + r16;
            int e = e0 + r;
            float s = 0.f;
            int jb = off2[e], je = off2[e+1];
            for (int j = jb; j < je; ++j)
                s += bu2f(ea[(size_t)j*64 + l]);
            sR[r][l] = f2bu(s);
        }
        __syncthreads();

        const int lr = l & 15, hq = l >> 4, lk = hq * 8;
        f32x4 acc[4] = {};
        #pragma unroll
        for (int kk = 0; kk < 2; ++kk) {
            bf16x8 b = *(const bf16x8*)&WT2[(size_t)(16*w + lr)*64 + kk*32 + lk];
            #pragma unroll
            for (int m = 0; m < 4; ++m) {
                bf16x8 a = *(const bf16x8*)&sR[16*m + lr][kk*32 + lk];
                acc[m] = __builtin_amdgcn_mfma_f32_16x16x32_bf16(a, b, acc[m], 0, 0, 0);
            }
        }
        int c = 16*w + lr;
        float bb = b2_[c], r0 = er0[c], r1 = er1[c];
        #pragma unroll
        for (int m = 0; m < 4; ++m)
            #pragma unroll
            for (int j = 0; j < 4; ++j) {
                int r = 16*m + 4*hq + j;
                size_t idx = (size_t)(e0 + r)*64 + c;
                e_out[idx] = bu2f(sB[r][c]) + r0 * bu2f(sE[r][c])
                           + r1 * silu_(acc[m][j] + bb);
            }
    } else {
        const int n = blk - 4096;
        float* he = (float*)&sR[0][0];
        float* hn = he + 192;
        for (int i = tid; i < 192; i += 256) he[i] = h2g2_e[(size_t)n*192 + i];
        for (int i = tid; i < 384; i += 256) hn[i] = h2g2_n[(size_t)n*384 + i];
        __syncthreads();
        const float SCALE = 1.0f / (6.4f * 3.0f);
        for (int i = tid; i < 768; i += 256) {
            float s;
            if (i < 256) {
                int a = i >> 6, j = i & 63;
                s = he[a]*he[j] + he[64+a]*he[64+j] + he[128+a]*he[128+j];
            } else {
                int i2 = i - 256;
                int a = i2 >> 7, j = i2 & 127;
                s = hn[a]*hn[j] + hn[128+a]*hn[128+j] + hn[256+a]*hn[256+j];
            }
            symcB[(size_t)n*768 + i] = f2bu(s * SCALE);
        }
    }
}

// ---------------------------------------------------------------------------
// Node finalize via MFMA.
// ---------------------------------------------------------------------------
__global__ __launch_bounds__(256) void k_node_mfma(
    const u16* __restrict__ symcB, const u16* __restrict__ NB,
    const float* __restrict__ node_ext, const float* __restrict__ msg,
    const u16* __restrict__ WsymT, const u16* __restrict__ WnsT,
    const float* __restrict__ bns, const float* __restrict__ bsym,
    const float* __restrict__ nr0, const float* __restrict__ nr1,
    const float* __restrict__ nr2,
    float* __restrict__ n_out)
{
    __shared__ __align__(16) u16 sA[32][264];
    const int tid = threadIdx.x;
    const int n0 = blockIdx.x * 32;
    const int w = tid >> 6, l = tid & 63;
    const int lr = l & 15, hq = l >> 4, lk = hq * 8;

    f32x4 accY[2][2] = {};
    f32x4 accS[2][2] = {};

    for (int chunk = 0; chunk < 3; ++chunk) {
        __syncthreads();
        #pragma unroll
        for (int f = tid; f < 1024; f += 256) {
            int r = f >> 5, c = f & 31;
            *(uint4*)&sA[r][8*c] =
                ((const uint4*)&symcB[(size_t)(n0 + r)*768 + chunk*256])[c];
        }
        __syncthreads();
        #pragma unroll
        for (int kk = 0; kk < 8; ++kk) {
            bf16x8 a[2], b[2];
            #pragma unroll
            for (int m = 0; m < 2; ++m)
                a[m] = *(const bf16x8*)&sA[16*m + lr][kk*32 + lk];
            #pragma unroll
            for (int nf = 0; nf < 2; ++nf)
                b[nf] = *(const bf16x8*)&WsymT[(size_t)(32*w + 16*nf + lr)*768
                                               + chunk*256 + kk*32 + lk];
            #pragma unroll
            for (int m = 0; m < 2; ++m)
                #pragma unroll
                for (int nf = 0; nf < 2; ++nf)
                    accY[m][nf] = __builtin_amdgcn_mfma_f32_16x16x32_bf16(a[m], b[nf], accY[m][nf], 0, 0, 0);
        }
    }

    __syncthreads();
    #pragma unroll
    for (int f = tid; f < 512; f += 256) {
        int r = f >> 4, c = f & 15;
        *(uint4*)&sA[r][8*c] = ((const uint4*)&NB[(size_t)(n0 + r)*128])[c];
    }
    __syncthreads();
    #pragma unroll
    for (int kk = 0; kk < 4; ++kk) {
        bf16x8 a[2], b[2];
        #pragma unroll
        for (int m = 0; m < 2; ++m)
            a[m] = *(const bf16x8*)&sA[16*m + lr][kk*32 + lk];
        #pragma unroll
        for (int nf = 0; nf < 2; ++nf)
            b[nf] = *(const bf16x8*)&WnsT[(size_t)(32*w + 16*nf + lr)*128 + kk*32 + lk];
        #pragma unroll
        for (int m = 0; m < 2; ++m)
            #pragma unroll
            for (int nf = 0; nf < 2; ++nf)
                accS[m][nf] = __builtin_amdgcn_mfma_f32_16x16x32_bf16(a[m], b[nf], accS[m][nf], 0, 0, 0);
    }

    #pragma unroll
    for (int nf = 0; nf < 2; ++nf) {
        int c = 32*w + 16*nf + lr;
        float bS = bns[c], bY = bsym[c];
        float r0 = nr0[c], r1 = nr1[c], r2 = nr2[c];
        #pragma unroll
        for (int m = 0; m < 2; ++m)
            #pragma unroll
            for (int j = 0; j < 4; ++j) {
                int r = 16*m + 4*hq + j;
                size_t idx = (size_t)(n0 + r)*128 + c;
                float self_ = silu_(accS[m][nf][j] + bS);
                float sym_  = silu_(accY[m][nf][j] + bY);
                n_out[idx] = node_ext[idx] + r0*self_ + r1*sym_
                           + r2 * msg[idx] * (1.0f / 6.4f);
            }
    }
}

// ---------------------------------------------------------------------------
extern "C" void kernel_launch(void* const* d_in, const int* in_sizes, int n_in,
                              void* d_out, int out_size, void* d_ws, size_t ws_size,
                              hipStream_t stream)
{
    const float* node_ext  = (const float*)d_in[0];
    const float* edge_ebd  = (const float*)d_in[1];
    const float* h2        = (const float*)d_in[2];
    const float* angle_ebd = (const float*)d_in[3];
    const float* sw        = (const float*)d_in[6];
    const float* a_sw      = (const float*)d_in[9];
    const int*  edge_index  = (const int*)d_in[10];
    const int*  angle_index = (const int*)d_in[11];
    const int* n2e     = edge_index;
    const int* n_ext2e = edge_index + NEDGE_;
    const int* n2a     = angle_index;
    const int* eij2a   = angle_index + NANGLE_;
    const int* eik2a   = angle_index + 2*NANGLE_;

    const float* Wns  = (const float*)d_in[12];
    const float* bns  = (const float*)d_in[13];
    const float* Wsym = (const float*)d_in[14];
    const float* bsym = (const float*)d_in[15];
    const float* Wne  = (const float*)d_in[16];
    const float* bne  = (const float*)d_in[17];
    const float* Wes  = (const float*)d_in[18];
    const float* bes  = (const float*)d_in[19];
    const float* W1   = (const float*)d_in[20];
    const float* b1   = (const float*)d_in[21];
    const float* W2   = (const float*)d_in[22];
    const float* b2_  = (const float*)d_in[23];
    const float* WA   = (const float*)d_in[24];
    const float* bA   = (const float*)d_in[25];
    const float* nr0  = (const float*)d_in[26];
    const float* nr1  = (const float*)d_in[27];
    const float* nr2  = (const float*)d_in[28];
    const float* er0  = (const float*)d_in[29];
    const float* er1  = (const float*)d_in[30];
    const float* ar0  = (const float*)d_in[31];

    // workspace layout
    char* wsp = (char*)d_ws;
    u16*   ea      = (u16*)wsp;    wsp += (size_t)NANGLE_ * 64 * 2;
    u16*   EB      = (u16*)wsp;    wsp += (size_t)NEDGE_ * 64 * 2;
    u16*   NB      = (u16*)wsp;    wsp += (size_t)NALL_ * 128 * 2;
    u16*   eselfO  = (u16*)wsp;    wsp += (size_t)NEDGE_ * 64 * 2;
    u16*   symcB   = (u16*)wsp;    wsp += (size_t)NLOC_ * 768 * 2;
    // zeroed region: [cnt | cnt2 | msg | h2g2_e | h2g2_n]
    int*   cnt     = (int*)wsp;    wsp += 4096 * 4;
    int*   cnt2    = (int*)wsp;    wsp += (size_t)NEDGE_ * 4;
    float* msg     = (float*)wsp;  wsp += (size_t)NLOC_ * 128 * 4;
    float* h2g2_e  = (float*)wsp;  wsp += (size_t)NLOC_ * 192 * 4;
    float* h2g2_n  = (float*)wsp;  wsp += (size_t)NLOC_ * 384 * 4;
    size_t zero_bytes = 4096*4 + (size_t)NEDGE_*4 + (size_t)NLOC_*128*4
                      + (size_t)NLOC_*192*4 + (size_t)NLOC_*384*4;
    int*   off     = (int*)wsp;    wsp += 4104 * 4;
    int*   cursor  = (int*)wsp;    wsp += 4096 * 4;
    int*   csr     = (int*)wsp;    wsp += (size_t)NEDGE_ * 4;
    int*   off2    = (int*)wsp;    wsp += ((size_t)NEDGE_ + 16) * 4;
    int*   cursor2 = (int*)wsp;    wsp += (size_t)NEDGE_ * 4;
    int*   bsum    = (int*)wsp;    wsp += 256 * 4;
    int*   boff    = (int*)wsp;    wsp += 256 * 4;
    int*   csr2    = (int*)wsp;    wsp += (size_t)NANGLE_ * 4;
    float* nconst  = (float*)wsp;  wsp += (size_t)NLOC_ * 192 * 4;
    float* nconstA = (float*)wsp;  wsp += (size_t)NLOC_ * 96 * 4;
    u16*   WTe     = (u16*)wsp;    wsp += 192 * 320 * 2;
    u16*   WTa2    = (u16*)wsp;    wsp += 96 * 160 * 2;
    u16*   WTaN    = (u16*)wsp;    wsp += 96 * 128 * 2;
    u16*   WT2     = (u16*)wsp;    wsp += 64 * 64 * 2;
    u16*   WsymT   = (u16*)wsp;    wsp += 128 * 768 * 2;
    u16*   WnsT    = (u16*)wsp;    wsp += 128 * 128 * 2;

    hipMemsetAsync(cnt, 0, zero_bytes, stream);

    float* n_out = (float*)d_out;
    float* e_out = n_out + (size_t)NLOC_ * 128;
    float* a_out = e_out + (size_t)NEDGE_ * 64;

    k_mega_prep <<<6252, 256, 0, stream>>>(Wne, Wes, W1, WA, W2, Wsym, Wns,
                                           node_ext, edge_ebd,
                                           n2e, eij2a,
                                           WTe, WTa2, WTaN, WT2, WsymT, WnsT,
                                           NB, EB, cnt, cnt2);
    k_scan_misc <<<385, 256, 0, stream>>>(cnt, off, cursor, cnt2, bsum,
                                          NB, WTe, WTaN, nconst, nconstA);
    k_scan2b <<<1, 256, 0, stream>>>(bsum, boff);
    k_scan2c <<<256, 256, 0, stream>>>(cnt2, boff, off2, cursor2);
    k_fill2  <<<2624, 256, 0, stream>>>(n2e, cursor, csr, eij2a, cursor2, csr2);

    k_edge_angle <<<16896, 256, 0, stream>>>(NB, EB, h2, sw, n2e, n_ext2e, csr,
                                             WTe, nconst, bne, bes,
                                             msg, h2g2_e, h2g2_n, eselfO,
                                             angle_ebd, a_sw,
                                             n2a, eij2a, eik2a, csr2,
                                             WTa2, nconstA, b1, bA, ar0,
                                             ea, a_out);
    k_fin <<<8192, 256, 0, stream>>>(EB, eselfO, ea, off2, WT2, b2_, er0, er1,
                                     e_out, h2g2_e, h2g2_n, symcB);
    k_node_mfma <<<NLOC_/32, 256, 0, stream>>>(symcB, NB, node_ext, msg,
                                               WsymT, WnsT, bns, bsym,
                                               nr0, nr1, nr2, n_out);
}

// Round 14
// 482.345 us; speedup vs baseline: 1.0971x; 1.0971x over previous
//
#include <hip/hip_runtime.h>
#include <hip/hip_bf16.h>

#define NLOC_   4096
#define NALL_   6144
#define NEDGE_  262144
#define NANGLE_ 409600

typedef __bf16 bf16x8 __attribute__((ext_vector_type(8)));
typedef float  f32x4  __attribute__((ext_vector_type(4)));
typedef unsigned short u16;

__device__ __forceinline__ float silu_(float x){ return x / (1.0f + __expf(-x)); }

__device__ __forceinline__ u16 f2bu(float f){
    union { float f; unsigned u; } v; v.f = f;
    unsigned r = v.u + 0x7fffu + ((v.u >> 16) & 1u);
    return (u16)(r >> 16);
}
__device__ __forceinline__ float bu2f(u16 b){
    union { unsigned u; float f; } v; v.u = ((unsigned)b) << 16; return v.f;
}
__device__ __forceinline__ void st_bf16x4(u16* dst, float4 v){
    unsigned lo = (unsigned)f2bu(v.x) | ((unsigned)f2bu(v.y) << 16);
    unsigned hi = (unsigned)f2bu(v.z) | ((unsigned)f2bu(v.w) << 16);
    *reinterpret_cast<uint2*>(dst) = make_uint2(lo, hi);
}

// ---------------------------------------------------------------------------
// L1 mega-prep: weight transposes + bf16 tables + CSR counts, block-ranged.
// ---------------------------------------------------------------------------
__global__ __launch_bounds__(256) void k_mega_prep(
    const float* __restrict__ Wne, const float* __restrict__ Wes,
    const float* __restrict__ W1,  const float* __restrict__ WA,
    const float* __restrict__ W2,  const float* __restrict__ Wsym,
    const float* __restrict__ Wns,
    const float* __restrict__ node_ext, const float* __restrict__ edge_ebd,
    const int* __restrict__ n2e, const int* __restrict__ eij2a,
    u16* __restrict__ WTe, u16* __restrict__ WTa2, u16* __restrict__ WTaN,
    u16* __restrict__ WT2, u16* __restrict__ WsymT, u16* __restrict__ WnsT,
    u16* __restrict__ NB, u16* __restrict__ EB,
    int* __restrict__ cnt, int* __restrict__ cnt2)
{
    const int b = blockIdx.x, tid = threadIdx.x;
    if (b < 812) {
        int i = b*256 + tid;
        if (i < 61440) {                       // WTe[192][320]
            int r = i/320, c = i - r*320;
            WTe[i] = f2bu(r < 128 ? Wne[c*128 + r] : Wes[c*64 + (r-128)]);
        } else if (i < 76800) {                // WTa2[96][160]
            int j = i - 61440; int r = j/160, c2 = j - r*160;
            int k = (c2 < 32) ? c2 : c2 + 128;
            WTa2[j] = f2bu(r < 64 ? W1[k*64 + r] : WA[k*32 + (r-64)]);
        } else if (i < 89088) {                // WTaN[96][128]
            int j = i - 76800; int r = j >> 7, c2 = j & 127;
            int k = c2 + 32;
            WTaN[j] = f2bu(r < 64 ? W1[k*64 + r] : WA[k*32 + (r-64)]);
        } else if (i < 93184) {                // WT2[64][64]
            int j = i - 89088; int r = j >> 6, c = j & 63;
            WT2[j] = f2bu(W2[c*64 + r]);
        } else if (i < 191488) {               // WsymT[128][768]
            int j = i - 93184; int r = j/768, c = j - r*768;
            WsymT[j] = f2bu(Wsym[c*128 + r]);
        } else {                               // WnsT[128][128]
            int j = i - 191488; int r = j >> 7, c = j & 127;
            WnsT[j] = f2bu(Wns[c*128 + r]);
        }
    } else if (b < 1580) {                     // NB
        int i = (b - 812)*256 + tid;
        float4 v = ((const float4*)node_ext)[i];
        st_bf16x4(&NB[(size_t)i*4], v);
    } else if (b < 3628) {                     // EB
        for (int i = (b - 1580)*256 + tid; i < NEDGE_*64/4; i += 2048*256) {
            float4 v = ((const float4*)edge_ebd)[i];
            st_bf16x4(&EB[(size_t)i*4], v);
        }
    } else if (b < 4652) {                     // count n2e
        int e = (b - 3628)*256 + tid;
        atomicAdd(&cnt[n2e[e]], 1);
    } else {                                   // count eij2a
        int a = (b - 4652)*256 + tid;
        atomicAdd(&cnt2[eij2a[a]], 1);
    }
}

// ---------------------------------------------------------------------------
// L2: block 0 = node scan; 1..256 = scan2a; 257..320 = nconst; 321..384 = nconstA.
// ---------------------------------------------------------------------------
__global__ __launch_bounds__(256) void k_scan_misc(
    const int* __restrict__ cnt, int* __restrict__ off, int* __restrict__ cursor,
    const int* __restrict__ cnt2, int* __restrict__ bsum,
    const u16* __restrict__ NB, const u16* __restrict__ WTe,
    const u16* __restrict__ WTaN,
    float* __restrict__ nconst, float* __restrict__ nconstA)
{
    __shared__ __align__(16) u16 sN[64][136];
    int* wa = (int*)&sN[0][0];
    const int b = blockIdx.x, t = threadIdx.x;

    if (b == 0) {
        int v[16]; int s = 0;
        #pragma unroll
        for (int k = 0; k < 16; ++k) { v[k] = s; s += cnt[16*t + k]; }
        wa[t] = s;
        __syncthreads();
        for (int d = 1; d < 256; d <<= 1) {
            int x = wa[t];
            int y = (t >= d) ? wa[t-d] : 0;
            __syncthreads();
            wa[t] = x + y;
            __syncthreads();
        }
        int excl = (t == 0) ? 0 : wa[t-1];
        #pragma unroll
        for (int k = 0; k < 16; ++k) {
            off[16*t + k]    = excl + v[k];
            cursor[16*t + k] = excl + v[k];
        }
        if (t == 255) off[4096] = excl + s;
    } else if (b <= 256) {
        int bb = b - 1;
        int4 v = ((const int4*)cnt2)[bb*256 + t];
        wa[t] = v.x + v.y + v.z + v.w;
        __syncthreads();
        for (int d = 128; d > 0; d >>= 1) {
            if (t < d) wa[t] += wa[t+d];
            __syncthreads();
        }
        if (t == 0) bsum[bb] = wa[0];
    } else if (b <= 320) {
        const int e0 = (b - 257) * 64;
        #pragma unroll
        for (int f = t; f < 1024; f += 256) {
            int r = f >> 4, c = f & 15;
            *(uint4*)&sN[r][8*c] = ((const uint4*)&NB[(size_t)(e0 + r)*128])[c];
        }
        __syncthreads();
        const int w = t >> 6, l = t & 63;
        const int lr = l & 15, hq = l >> 4, lk = hq * 8;
        f32x4 acc[4][3] = {};
        #pragma unroll
        for (int kk = 0; kk < 4; ++kk) {
            bf16x8 a[4], bb[3];
            #pragma unroll
            for (int m = 0; m < 4; ++m)
                a[m] = *(const bf16x8*)&sN[16*m + lr][kk*32 + lk];
            #pragma unroll
            for (int nf = 0; nf < 3; ++nf)
                bb[nf] = *(const bf16x8*)&WTe[(size_t)(48*w + 16*nf + lr)*320 + kk*32 + lk];
            #pragma unroll
            for (int m = 0; m < 4; ++m)
                #pragma unroll
                for (int nf = 0; nf < 3; ++nf)
                    acc[m][nf] = __builtin_amdgcn_mfma_f32_16x16x32_bf16(a[m], bb[nf], acc[m][nf], 0, 0, 0);
        }
        #pragma unroll
        for (int nf = 0; nf < 3; ++nf) {
            int c = 48*w + 16*nf + lr;
            #pragma unroll
            for (int m = 0; m < 4; ++m)
                #pragma unroll
                for (int j = 0; j < 4; ++j) {
                    int r = 16*m + 4*hq + j;
                    nconst[(size_t)(e0 + r)*192 + c] = acc[m][nf][j];
                }
        }
    } else {
        const int n0 = (b - 321) * 64;
        #pragma unroll
        for (int f = t; f < 1024; f += 256) {
            int r = f >> 4, c = f & 15;
            *(uint4*)&sN[r][8*c] = ((const uint4*)&NB[(size_t)(n0 + r)*128])[c];
        }
        __syncthreads();
        const int w = t >> 6, l = t & 63;
        const int lr = l & 15, hq = l >> 4, lk = hq * 8;
        f32x4 acc[6] = {};
        #pragma unroll
        for (int kk = 0; kk < 4; ++kk) {
            bf16x8 a = *(const bf16x8*)&sN[16*w + lr][kk*32 + lk];
            #pragma unroll
            for (int nf = 0; nf < 6; ++nf) {
                bf16x8 bb = *(const bf16x8*)&WTaN[(size_t)(16*nf + lr)*128 + kk*32 + lk];
                acc[nf] = __builtin_amdgcn_mfma_f32_16x16x32_bf16(a, bb, acc[nf], 0, 0, 0);
            }
        }
        #pragma unroll
        for (int nf = 0; nf < 6; ++nf) {
            int c = 16*nf + lr;
            #pragma unroll
            for (int j = 0; j < 4; ++j) {
                int r = 16*w + 4*hq + j;
                nconstA[(size_t)(n0 + r)*96 + c] = acc[nf][j];
            }
        }
    }
}

__global__ void k_scan2b(const int* __restrict__ bsum, int* __restrict__ boff)
{
    __shared__ int wa[256];
    int t = threadIdx.x;
    wa[t] = bsum[t];
    __syncthreads();
    for (int d = 1; d < 256; d <<= 1) {
        int x = wa[t];
        int y = (t >= d) ? wa[t-d] : 0;
        __syncthreads();
        wa[t] = x + y;
        __syncthreads();
    }
    boff[t] = (t == 0) ? 0 : wa[t-1];
}

__global__ void k_scan2c(const int* __restrict__ cnt2, const int* __restrict__ boff,
                         int* __restrict__ off2, int* __restrict__ cursor2)
{
    __shared__ int wa[256];
    int b = blockIdx.x, t = threadIdx.x;
    int4 v = ((const int4*)cnt2)[b*256 + t];
    int s1 = v.x, s2 = s1 + v.y, s3 = s2 + v.z, s4 = s3 + v.w;
    wa[t] = s4;
    __syncthreads();
    for (int d = 1; d < 256; d <<= 1) {
        int x = wa[t];
        int y = (t >= d) ? wa[t-d] : 0;
        __syncthreads();
        wa[t] = x + y;
        __syncthreads();
    }
    int base = boff[b] + ((t == 0) ? 0 : wa[t-1]);
    int i = (b*256 + t)*4;
    off2[i]   = base;      cursor2[i]   = base;
    off2[i+1] = base + s1; cursor2[i+1] = base + s1;
    off2[i+2] = base + s2; cursor2[i+2] = base + s2;
    off2[i+3] = base + s3; cursor2[i+3] = base + s3;
    if (b == 255 && t == 255) off2[NEDGE_] = NANGLE_;
}

// L5: fused fills. [0,1024) edge csr; [1024,2624) angle csr2 (sorted list).
__global__ void k_fill2(const int* __restrict__ n2e, int* __restrict__ cursor,
                        int* __restrict__ csr,
                        const int* __restrict__ eij2a, int* __restrict__ cursor2,
                        int* __restrict__ csr2)
{
    int b = blockIdx.x;
    if (b < 1024) {
        int e = b*256 + threadIdx.x;
        int pos = atomicAdd(&cursor[n2e[e]], 1);
        csr[pos] = e;
    } else {
        int a = (b - 1024)*256 + threadIdx.x;
        int pos = atomicAdd(&cursor2[eij2a[a]], 1);
        csr2[pos] = a;
    }
}

// ---------------------------------------------------------------------------
// Flat edge GEMM over CSR-ordered tiles + fused segmented h2g2.
// LDS-slim: single sHa[576] with LDS atomicAdd cross-wave reduce -> ~30 KB
// LDS -> 5 blocks/CU.
// ---------------------------------------------------------------------------
__global__ __launch_bounds__(256, 5) void k_edge_flat(
    const u16* __restrict__ NB, const u16* __restrict__ EB,
    const float* __restrict__ h2, const float* __restrict__ sw,
    const int* __restrict__ n2e, const int* __restrict__ n_ext2e,
    const int* __restrict__ csr,
    const u16* __restrict__ WTe, const float* __restrict__ nconst,
    const float* __restrict__ bne, const float* __restrict__ bes,
    float* __restrict__ msg,
    float* __restrict__ h2g2_e, float* __restrict__ h2g2_n,
    u16* __restrict__ eselfO)
{
    __shared__ __align__(16) u16 sA[64][200];
    __shared__ float sHa[576];
    __shared__ int   s_eid[64];
    __shared__ int   s_node[64];
    __shared__ int   s_g[64];
    __shared__ float s_sw[64];
    __shared__ float s_h2[64][3];
    __shared__ int   s_segstart[65];
    __shared__ int   s_nseg;

    const int tid = threadIdx.x;
    const int w  = tid >> 6, l = tid & 63;
    const int lr = l & 15, hq = l >> 4, lk = hq * 8;
    const int base = blockIdx.x * 64;

    if (tid < 64) {
        int e = csr[base + tid];
        s_eid[tid]  = e;
        s_node[tid] = n2e[e];
        s_g[tid]    = n_ext2e[e];
        s_sw[tid]   = sw[e];
        s_h2[tid][0] = h2[e*3];
        s_h2[tid][1] = h2[e*3+1];
        s_h2[tid][2] = h2[e*3+2];
    }
    __syncthreads();

    if (tid < 64) {
        bool flag = (tid == 0) || (s_node[tid] != s_node[tid-1]);
        unsigned long long mask = __ballot(flag);
        if (flag) {
            int sid = __popcll(mask & ((1ull << tid) - 1ull));
            s_segstart[sid] = tid;
        }
        if (tid == 0) {
            int ns = __popcll(mask);
            s_nseg = ns;
            s_segstart[ns] = 64;
        }
    }

    #pragma unroll
    for (int f = tid; f < 1024; f += 256) {
        int r = f >> 4, c = f & 15;
        *(uint4*)&sA[r][8*c] = ((const uint4*)&NB[(size_t)s_g[r]*128])[c];
    }
    #pragma unroll
    for (int f = tid; f < 512; f += 256) {
        int r = f >> 3, c = f & 7;
        *(uint4*)&sA[r][128 + 8*c] = ((const uint4*)&EB[(size_t)s_eid[r]*64])[c];
    }
    __syncthreads();

    float bias[3];
    int   cful[3];
    #pragma unroll
    for (int nf = 0; nf < 3; ++nf) {
        int c = 48*w + 16*nf + lr;
        cful[nf] = c;
        bias[nf] = (c < 128) ? bne[c] : bes[c-128];
    }

    f32x4 acc[4][3] = {};
    #pragma unroll
    for (int kk = 0; kk < 6; ++kk) {
        bf16x8 a[4], b[3];
        #pragma unroll
        for (int m = 0; m < 4; ++m)
            a[m] = *(const bf16x8*)&sA[16*m + lr][kk*32 + lk];
        #pragma unroll
        for (int nf = 0; nf < 3; ++nf)
            b[nf] = *(const bf16x8*)&WTe[(size_t)cful[nf]*320 + 128 + kk*32 + lk];
        #pragma unroll
        for (int m = 0; m < 4; ++m)
            #pragma unroll
            for (int nf = 0; nf < 3; ++nf)
                acc[m][nf] = __builtin_amdgcn_mfma_f32_16x16x32_bf16(a[m], b[nf], acc[m][nf], 0, 0, 0);
    }

    #pragma unroll
    for (int nf = 0; nf < 3; ++nf) {
        int c = cful[nf];
        if (c < 128) {
            #pragma unroll
            for (int m = 0; m < 4; ++m)
                #pragma unroll
                for (int j = 0; j < 4; ++j) {
                    int r = 16*m + 4*hq + j;
                    float ncv = nconst[(size_t)s_node[r]*192 + c];
                    acc[m][nf][j] = silu_(acc[m][nf][j] + ncv + bias[nf]) * s_sw[r];
                }
        } else {
            int c2 = c - 128;
            #pragma unroll
            for (int m = 0; m < 4; ++m)
                #pragma unroll
                for (int j = 0; j < 4; ++j) {
                    int r = 16*m + 4*hq + j;
                    float ncv = nconst[(size_t)s_node[r]*192 + c];
                    eselfO[(size_t)s_eid[r]*64 + c2] =
                        f2bu(silu_(acc[m][nf][j] + ncv + bias[nf]));
                }
        }
    }

    // ---- segmented msg reduction ----
    const int nseg = s_nseg;
    for (int s = 0; s < nseg; ++s) {
        int rs = s_segstart[s], re = s_segstart[s+1];
        int nd = s_node[rs];
        #pragma unroll
        for (int nf = 0; nf < 3; ++nf) {
            if (cful[nf] >= 128) continue;
            float v = 0.f;
            #pragma unroll
            for (int m = 0; m < 4; ++m)
                #pragma unroll
                for (int j = 0; j < 4; ++j) {
                    int r = 16*m + 4*hq + j;
                    v += (r >= rs && r < re) ? acc[m][nf][j] : 0.f;
                }
            v += __shfl_xor(v, 16);
            v += __shfl_xor(v, 32);
            if (hq == 0) atomicAdd(&msg[(size_t)nd*128 + cful[nf]], v);
        }
    }

    // ---- segmented h2g2 accumulation (LDS-atomic cross-wave reduce) ----
    for (int s = 0; s < nseg; ++s) {
        int rs = s_segstart[s], re = s_segstart[s+1];
        int nd = s_node[rs];
        int lo = max(16*w, rs), hi = min(16*w + 16, re);

        __syncthreads();                   // previous flush done / sA stable
        for (int i = tid; i < 576; i += 256) sHa[i] = 0.f;
        __syncthreads();

        if (lo < hi) {
            float hacc[9] = {0.f,0.f,0.f,0.f,0.f,0.f,0.f,0.f,0.f};
            for (int r = lo; r < hi; ++r) {
                float swv = s_sw[r];
                float s0 = s_h2[r][0] * swv;
                float s1 = s_h2[r][1] * swv;
                float s2 = s_h2[r][2] * swv;
                float eb = bu2f(sA[r][128 + l]);
                float n0 = bu2f(sA[r][l]);
                float n1 = bu2f(sA[r][64 + l]);
                hacc[0] = fmaf(s0, eb, hacc[0]);
                hacc[1] = fmaf(s1, eb, hacc[1]);
                hacc[2] = fmaf(s2, eb, hacc[2]);
                hacc[3] = fmaf(s0, n0, hacc[3]);
                hacc[4] = fmaf(s0, n1, hacc[4]);
                hacc[5] = fmaf(s1, n0, hacc[5]);
                hacc[6] = fmaf(s1, n1, hacc[6]);
                hacc[7] = fmaf(s2, n0, hacc[7]);
                hacc[8] = fmaf(s2, n1, hacc[8]);
            }
            #pragma unroll
            for (int q = 0; q < 3; ++q) atomicAdd(&sHa[q*64 + l], hacc[q]);
            #pragma unroll
            for (int q = 0; q < 6; ++q) atomicAdd(&sHa[192 + q*64 + l], hacc[3+q]);
        }
        __syncthreads();

        for (int i = tid; i < 576; i += 256) {
            float v = sHa[i];
            if (i < 192) atomicAdd(&h2g2_e[(size_t)nd*192 + i], v);
            else         atomicAdd(&h2g2_n[(size_t)nd*384 + (i - 192)], v);
        }
    }
}

// ---------------------------------------------------------------------------
// Angle GEMM via MFMA, eij-SORTED order; angle_ebd staged f32->bf16 directly.
// ---------------------------------------------------------------------------
__global__ __launch_bounds__(256) void k_angle_mfma(
    const u16* __restrict__ EB, const float* __restrict__ angle_ebd,
    const float* __restrict__ a_sw,
    const int* __restrict__ n2a, const int* __restrict__ eij2a,
    const int* __restrict__ eik2a, const int* __restrict__ csr2,
    const u16* __restrict__ WTa2, const float* __restrict__ nconstA,
    const float* __restrict__ b1, const float* __restrict__ bA,
    const float* __restrict__ a_res0,
    u16* __restrict__ ea, float* __restrict__ a_out)
{
    __shared__ __align__(16) u16 sA[32][168];
    __shared__ __align__(16) u16 sEA[32][64];
    __shared__ int s_a[32], s_nd[32], s_ij[32], s_ik[32];
    __shared__ float s_asw[32];
    const int tid = threadIdx.x;
    const int p0 = blockIdx.x * 32;

    if (tid < 32) {
        int a = csr2[p0 + tid];
        s_a[tid]  = a;
        s_nd[tid] = n2a[a];
        s_ij[tid] = eij2a[a];
        s_ik[tid] = eik2a[a];
        s_asw[tid] = a_sw[a];
    }
    __syncthreads();

    {                                                // angle_ebd f32 gather
        int r = tid >> 3, c = tid & 7;
        st_bf16x4(&sA[r][4*c], ((const float4*)angle_ebd)[(size_t)s_a[r]*8 + c]);
    }
    {
        int r = tid >> 3, c = tid & 7;
        *(uint4*)&sA[r][32 + 8*c] = ((const uint4*)&EB[(size_t)s_ik[r]*64])[c];
        *(uint4*)&sA[r][96 + 8*c] = ((const uint4*)&EB[(size_t)s_ij[r]*64])[c];
    }
    __syncthreads();

    const int w = tid >> 6, l = tid & 63;
    const int lr = l & 15, hq = l >> 4, lk = hq * 8;
    const int mrow  = (w & 1) * 16;
    const int nbase = (w >> 1) * 48;

    f32x4 acc[3] = {};
    #pragma unroll
    for (int kk = 0; kk < 5; ++kk) {
        bf16x8 a = *(const bf16x8*)&sA[mrow + lr][kk*32 + lk];
        #pragma unroll
        for (int nf = 0; nf < 3; ++nf) {
            bf16x8 b = *(const bf16x8*)&WTa2[(size_t)(nbase + 16*nf + lr)*160 + kk*32 + lk];
            acc[nf] = __builtin_amdgcn_mfma_f32_16x16x32_bf16(a, b, acc[nf], 0, 0, 0);
        }
    }

    #pragma unroll
    for (int nf = 0; nf < 3; ++nf) {
        int c = nbase + 16*nf + lr;
        if (c < 64) {
            float bb = b1[c];
            #pragma unroll
            for (int j = 0; j < 4; ++j) {
                int r = mrow + 4*hq + j;
                float nca = nconstA[(size_t)s_nd[r]*96 + c];
                sEA[r][c] = f2bu(silu_(acc[nf][j] + nca + bb) * s_asw[r]);
            }
        } else {
            int c2 = c - 64;
            float bb = bA[c2], rr = a_res0[c2];
            #pragma unroll
            for (int j = 0; j < 4; ++j) {
                int r = mrow + 4*hq + j;
                float nca = nconstA[(size_t)s_nd[r]*96 + c];
                a_out[(size_t)s_a[r]*32 + c2] =
                    bu2f(sA[r][c2]) + rr * silu_(acc[nf][j] + nca + bb);
            }
        }
    }
    __syncthreads();

    {                                                // sequential ea store
        int r = tid >> 3, c = tid & 7;
        *(uint4*)&ea[((size_t)(p0 + r))*64 + 8*c] = *(const uint4*)&sEA[r][8*c];
    }
}

// ---------------------------------------------------------------------------
// L8 fused: [0,4096) edgefin; [4096,8192) symc.
// ---------------------------------------------------------------------------
__global__ __launch_bounds__(256) void k_fin(
    const u16* __restrict__ EB, const u16* __restrict__ eselfO,
    const u16* __restrict__ ea, const int* __restrict__ off2,
    const u16* __restrict__ WT2,
    const float* __restrict__ b2_, const float* __restrict__ er0,
    const float* __restrict__ er1,
    float* __restrict__ e_out,
    const float* __restrict__ h2g2_e, const float* __restrict__ h2g2_n,
    u16* __restrict__ symcB)
{
    __shared__ __align__(16) u16 sR[64][72];
    __shared__ __align__(16) u16 sE[64][72];
    __shared__ __align__(16) u16 sB[64][72];
    const int tid = threadIdx.x;
    const int blk = blockIdx.x;

    if (blk < 4096) {
        const int e0 = blk * 64;
        const int w = tid >> 6, l = tid & 63;

        #pragma unroll
        for (int f = tid; f < 512; f += 256) {
            int r = f >> 3, c = f & 7;
            *(uint4*)&sB[r][8*c] = ((const uint4*)&EB[(size_t)(e0 + r)*64])[c];
            *(uint4*)&sE[r][8*c] = ((const uint4*)&eselfO[(size_t)(e0 + r)*64])[c];
        }

        #pragma unroll
        for (int r16 = 0; r16 < 16; ++r16) {
            int r = w*16 + r16;
            int e = e0 + r;
            float s = 0.f;
            int jb = off2[e], je = off2[e+1];
            for (int j = jb; j < je; ++j)
                s += bu2f(ea[(size_t)j*64 + l]);
            sR[r][l] = f2bu(s);
        }
        __syncthreads();

        const int lr = l & 15, hq = l >> 4, lk = hq * 8;
        f32x4 acc[4] = {};
        #pragma unroll
        for (int kk = 0; kk < 2; ++kk) {
            bf16x8 b = *(const bf16x8*)&WT2[(size_t)(16*w + lr)*64 + kk*32 + lk];
            #pragma unroll
            for (int m = 0; m < 4; ++m) {
                bf16x8 a = *(const bf16x8*)&sR[16*m + lr][kk*32 + lk];
                acc[m] = __builtin_amdgcn_mfma_f32_16x16x32_bf16(a, b, acc[m], 0, 0, 0);
            }
        }
        int c = 16*w + lr;
        float bb = b2_[c], r0 = er0[c], r1 = er1[c];
        #pragma unroll
        for (int m = 0; m < 4; ++m)
            #pragma unroll
            for (int j = 0; j < 4; ++j) {
                int r = 16*m + 4*hq + j;
                size_t idx = (size_t)(e0 + r)*64 + c;
                e_out[idx] = bu2f(sB[r][c]) + r0 * bu2f(sE[r][c])
                           + r1 * silu_(acc[m][j] + bb);
            }
    } else {
        const int n = blk - 4096;
        float* he = (float*)&sR[0][0];
        float* hn = he + 192;
        for (int i = tid; i < 192; i += 256) he[i] = h2g2_e[(size_t)n*192 + i];
        for (int i = tid; i < 384; i += 256) hn[i] = h2g2_n[(size_t)n*384 + i];
        __syncthreads();
        const float SCALE = 1.0f / (6.4f * 3.0f);
        for (int i = tid; i < 768; i += 256) {
            float s;
            if (i < 256) {
                int a = i >> 6, j = i & 63;
                s = he[a]*he[j] + he[64+a]*he[64+j] + he[128+a]*he[128+j];
            } else {
                int i2 = i - 256;
                int a = i2 >> 7, j = i2 & 127;
                s = hn[a]*hn[j] + hn[128+a]*hn[128+j] + hn[256+a]*hn[256+j];
            }
            symcB[(size_t)n*768 + i] = f2bu(s * SCALE);
        }
    }
}

// ---------------------------------------------------------------------------
// Node finalize via MFMA.
// ---------------------------------------------------------------------------
__global__ __launch_bounds__(256) void k_node_mfma(
    const u16* __restrict__ symcB, const u16* __restrict__ NB,
    const float* __restrict__ node_ext, const float* __restrict__ msg,
    const u16* __restrict__ WsymT, const u16* __restrict__ WnsT,
    const float* __restrict__ bns, const float* __restrict__ bsym,
    const float* __restrict__ nr0, const float* __restrict__ nr1,
    const float* __restrict__ nr2,
    float* __restrict__ n_out)
{
    __shared__ __align__(16) u16 sA[32][264];
    const int tid = threadIdx.x;
    const int n0 = blockIdx.x * 32;
    const int w = tid >> 6, l = tid & 63;
    const int lr = l & 15, hq = l >> 4, lk = hq * 8;

    f32x4 accY[2][2] = {};
    f32x4 accS[2][2] = {};

    for (int chunk = 0; chunk < 3; ++chunk) {
        __syncthreads();
        #pragma unroll
        for (int f = tid; f < 1024; f += 256) {
            int r = f >> 5, c = f & 31;
            *(uint4*)&sA[r][8*c] =
                ((const uint4*)&symcB[(size_t)(n0 + r)*768 + chunk*256])[c];
        }
        __syncthreads();
        #pragma unroll
        for (int kk = 0; kk < 8; ++kk) {
            bf16x8 a[2], b[2];
            #pragma unroll
            for (int m = 0; m < 2; ++m)
                a[m] = *(const bf16x8*)&sA[16*m + lr][kk*32 + lk];
            #pragma unroll
            for (int nf = 0; nf < 2; ++nf)
                b[nf] = *(const bf16x8*)&WsymT[(size_t)(32*w + 16*nf + lr)*768
                                               + chunk*256 + kk*32 + lk];
            #pragma unroll
            for (int m = 0; m < 2; ++m)
                #pragma unroll
                for (int nf = 0; nf < 2; ++nf)
                    accY[m][nf] = __builtin_amdgcn_mfma_f32_16x16x32_bf16(a[m], b[nf], accY[m][nf], 0, 0, 0);
        }
    }

    __syncthreads();
    #pragma unroll
    for (int f = tid; f < 512; f += 256) {
        int r = f >> 4, c = f & 15;
        *(uint4*)&sA[r][8*c] = ((const uint4*)&NB[(size_t)(n0 + r)*128])[c];
    }
    __syncthreads();
    #pragma unroll
    for (int kk = 0; kk < 4; ++kk) {
        bf16x8 a[2], b[2];
        #pragma unroll
        for (int m = 0; m < 2; ++m)
            a[m] = *(const bf16x8*)&sA[16*m + lr][kk*32 + lk];
        #pragma unroll
        for (int nf = 0; nf < 2; ++nf)
            b[nf] = *(const bf16x8*)&WnsT[(size_t)(32*w + 16*nf + lr)*128 + kk*32 + lk];
        #pragma unroll
        for (int m = 0; m < 2; ++m)
            #pragma unroll
            for (int nf = 0; nf < 2; ++nf)
                accS[m][nf] = __builtin_amdgcn_mfma_f32_16x16x32_bf16(a[m], b[nf], accS[m][nf], 0, 0, 0);
    }

    #pragma unroll
    for (int nf = 0; nf < 2; ++nf) {
        int c = 32*w + 16*nf + lr;
        float bS = bns[c], bY = bsym[c];
        float r0 = nr0[c], r1 = nr1[c], r2 = nr2[c];
        #pragma unroll
        for (int m = 0; m < 2; ++m)
            #pragma unroll
            for (int j = 0; j < 4; ++j) {
                int r = 16*m + 4*hq + j;
                size_t idx = (size_t)(n0 + r)*128 + c;
                float self_ = silu_(accS[m][nf][j] + bS);
                float sym_  = silu_(accY[m][nf][j] + bY);
                n_out[idx] = node_ext[idx] + r0*self_ + r1*sym_
                           + r2 * msg[idx] * (1.0f / 6.4f);
            }
    }
}

// ---------------------------------------------------------------------------
extern "C" void kernel_launch(void* const* d_in, const int* in_sizes, int n_in,
                              void* d_out, int out_size, void* d_ws, size_t ws_size,
                              hipStream_t stream)
{
    const float* node_ext  = (const float*)d_in[0];
    const float* edge_ebd  = (const float*)d_in[1];
    const float* h2        = (const float*)d_in[2];
    const float* angle_ebd = (const float*)d_in[3];
    const float* sw        = (const float*)d_in[6];
    const float* a_sw      = (const float*)d_in[9];
    const int*  edge_index  = (const int*)d_in[10];
    const int*  angle_index = (const int*)d_in[11];
    const int* n2e     = edge_index;
    const int* n_ext2e = edge_index + NEDGE_;
    const int* n2a     = angle_index;
    const int* eij2a   = angle_index + NANGLE_;
    const int* eik2a   = angle_index + 2*NANGLE_;

    const float* Wns  = (const float*)d_in[12];
    const float* bns  = (const float*)d_in[13];
    const float* Wsym = (const float*)d_in[14];
    const float* bsym = (const float*)d_in[15];
    const float* Wne  = (const float*)d_in[16];
    const float* bne  = (const float*)d_in[17];
    const float* Wes  = (const float*)d_in[18];
    const float* bes  = (const float*)d_in[19];
    const float* W1   = (const float*)d_in[20];
    const float* b1   = (const float*)d_in[21];
    const float* W2   = (const float*)d_in[22];
    const float* b2_  = (const float*)d_in[23];
    const float* WA   = (const float*)d_in[24];
    const float* bA   = (const float*)d_in[25];
    const float* nr0  = (const float*)d_in[26];
    const float* nr1  = (const float*)d_in[27];
    const float* nr2  = (const float*)d_in[28];
    const float* er0  = (const float*)d_in[29];
    const float* er1  = (const float*)d_in[30];
    const float* ar0  = (const float*)d_in[31];

    // workspace layout
    char* wsp = (char*)d_ws;
    u16*   ea      = (u16*)wsp;    wsp += (size_t)NANGLE_ * 64 * 2;
    u16*   EB      = (u16*)wsp;    wsp += (size_t)NEDGE_ * 64 * 2;
    u16*   NB      = (u16*)wsp;    wsp += (size_t)NALL_ * 128 * 2;
    u16*   eselfO  = (u16*)wsp;    wsp += (size_t)NEDGE_ * 64 * 2;
    u16*   symcB   = (u16*)wsp;    wsp += (size_t)NLOC_ * 768 * 2;
    // zeroed region: [cnt | cnt2 | msg | h2g2_e | h2g2_n]
    int*   cnt     = (int*)wsp;    wsp += 4096 * 4;
    int*   cnt2    = (int*)wsp;    wsp += (size_t)NEDGE_ * 4;
    float* msg     = (float*)wsp;  wsp += (size_t)NLOC_ * 128 * 4;
    float* h2g2_e  = (float*)wsp;  wsp += (size_t)NLOC_ * 192 * 4;
    float* h2g2_n  = (float*)wsp;  wsp += (size_t)NLOC_ * 384 * 4;
    size_t zero_bytes = 4096*4 + (size_t)NEDGE_*4 + (size_t)NLOC_*128*4
                      + (size_t)NLOC_*192*4 + (size_t)NLOC_*384*4;
    int*   off     = (int*)wsp;    wsp += 4104 * 4;
    int*   cursor  = (int*)wsp;    wsp += 4096 * 4;
    int*   csr     = (int*)wsp;    wsp += (size_t)NEDGE_ * 4;
    int*   off2    = (int*)wsp;    wsp += ((size_t)NEDGE_ + 16) * 4;
    int*   cursor2 = (int*)wsp;    wsp += (size_t)NEDGE_ * 4;
    int*   bsum    = (int*)wsp;    wsp += 256 * 4;
    int*   boff    = (int*)wsp;    wsp += 256 * 4;
    int*   csr2    = (int*)wsp;    wsp += (size_t)NANGLE_ * 4;
    float* nconst  = (float*)wsp;  wsp += (size_t)NLOC_ * 192 * 4;
    float* nconstA = (float*)wsp;  wsp += (size_t)NLOC_ * 96 * 4;
    u16*   WTe     = (u16*)wsp;    wsp += 192 * 320 * 2;
    u16*   WTa2    = (u16*)wsp;    wsp += 96 * 160 * 2;
    u16*   WTaN    = (u16*)wsp;    wsp += 96 * 128 * 2;
    u16*   WT2     = (u16*)wsp;    wsp += 64 * 64 * 2;
    u16*   WsymT   = (u16*)wsp;    wsp += 128 * 768 * 2;
    u16*   WnsT    = (u16*)wsp;    wsp += 128 * 128 * 2;

    hipMemsetAsync(cnt, 0, zero_bytes, stream);

    float* n_out = (float*)d_out;
    float* e_out = n_out + (size_t)NLOC_ * 128;
    float* a_out = e_out + (size_t)NEDGE_ * 64;

    k_mega_prep <<<6252, 256, 0, stream>>>(Wne, Wes, W1, WA, W2, Wsym, Wns,
                                           node_ext, edge_ebd,
                                           n2e, eij2a,
                                           WTe, WTa2, WTaN, WT2, WsymT, WnsT,
                                           NB, EB, cnt, cnt2);
    k_scan_misc <<<385, 256, 0, stream>>>(cnt, off, cursor, cnt2, bsum,
                                          NB, WTe, WTaN, nconst, nconstA);
    k_scan2b <<<1, 256, 0, stream>>>(bsum, boff);
    k_scan2c <<<256, 256, 0, stream>>>(cnt2, boff, off2, cursor2);
    k_fill2  <<<2624, 256, 0, stream>>>(n2e, cursor, csr, eij2a, cursor2, csr2);

    k_edge_flat <<<NEDGE_/64, 256, 0, stream>>>(NB, EB, h2, sw, n2e, n_ext2e, csr,
                                                WTe, nconst, bne, bes,
                                                msg, h2g2_e, h2g2_n, eselfO);
    k_angle_mfma <<<NANGLE_/32, 256, 0, stream>>>(EB, angle_ebd, a_sw,
                                                  n2a, eij2a, eik2a, csr2,
                                                  WTa2, nconstA, b1, bA, ar0,
                                                  ea, a_out);
    k_fin <<<8192, 256, 0, stream>>>(EB, eselfO, ea, off2, WT2, b2_, er0, er1,
                                     e_out, h2g2_e, h2g2_n, symcB);
    k_node_mfma <<<NLOC_/32, 256, 0, stream>>>(symcB, NB, node_ext, msg,
                                               WsymT, WnsT, bns, bsym,
                                               nr0, nr1, nr2, n_out);
}

// Round 15
// 423.560 us; speedup vs baseline: 1.2494x; 1.1388x over previous
//
#include <hip/hip_runtime.h>
#include <hip/hip_bf16.h>

#define NLOC_   4096
#define NALL_   6144
#define NEDGE_  262144
#define NANGLE_ 409600

typedef __bf16 bf16x8 __attribute__((ext_vector_type(8)));
typedef float  f32x4  __attribute__((ext_vector_type(4)));
typedef unsigned short u16;

__device__ __forceinline__ float silu_(float x){ return x / (1.0f + __expf(-x)); }

__device__ __forceinline__ u16 f2bu(float f){
    union { float f; unsigned u; } v; v.f = f;
    unsigned r = v.u + 0x7fffu + ((v.u >> 16) & 1u);
    return (u16)(r >> 16);
}
__device__ __forceinline__ float bu2f(u16 b){
    union { unsigned u; float f; } v; v.u = ((unsigned)b) << 16; return v.f;
}
__device__ __forceinline__ void st_bf16x4(u16* dst, float4 v){
    unsigned lo = (unsigned)f2bu(v.x) | ((unsigned)f2bu(v.y) << 16);
    unsigned hi = (unsigned)f2bu(v.z) | ((unsigned)f2bu(v.w) << 16);
    *reinterpret_cast<uint2*>(dst) = make_uint2(lo, hi);
}

// ---------------------------------------------------------------------------
// L1 mega-prep: weight transposes + bf16 tables + CSR counts, block-ranged.
// ---------------------------------------------------------------------------
__global__ __launch_bounds__(256) void k_mega_prep(
    const float* __restrict__ Wne, const float* __restrict__ Wes,
    const float* __restrict__ W1,  const float* __restrict__ WA,
    const float* __restrict__ W2,  const float* __restrict__ Wsym,
    const float* __restrict__ Wns,
    const float* __restrict__ node_ext, const float* __restrict__ edge_ebd,
    const int* __restrict__ n2e, const int* __restrict__ eij2a,
    u16* __restrict__ WTe, u16* __restrict__ WTa2, u16* __restrict__ WTaN,
    u16* __restrict__ WT2, u16* __restrict__ WsymT, u16* __restrict__ WnsT,
    u16* __restrict__ NB, u16* __restrict__ EB,
    int* __restrict__ cnt, int* __restrict__ cnt2)
{
    const int b = blockIdx.x, tid = threadIdx.x;
    if (b < 812) {
        int i = b*256 + tid;
        if (i < 61440) {                       // WTe[192][320]
            int r = i/320, c = i - r*320;
            WTe[i] = f2bu(r < 128 ? Wne[c*128 + r] : Wes[c*64 + (r-128)]);
        } else if (i < 76800) {                // WTa2[96][160]
            int j = i - 61440; int r = j/160, c2 = j - r*160;
            int k = (c2 < 32) ? c2 : c2 + 128;
            WTa2[j] = f2bu(r < 64 ? W1[k*64 + r] : WA[k*32 + (r-64)]);
        } else if (i < 89088) {                // WTaN[96][128]
            int j = i - 76800; int r = j >> 7, c2 = j & 127;
            int k = c2 + 32;
            WTaN[j] = f2bu(r < 64 ? W1[k*64 + r] : WA[k*32 + (r-64)]);
        } else if (i < 93184) {                // WT2[64][64]
            int j = i - 89088; int r = j >> 6, c = j & 63;
            WT2[j] = f2bu(W2[c*64 + r]);
        } else if (i < 191488) {               // WsymT[128][768]
            int j = i - 93184; int r = j/768, c = j - r*768;
            WsymT[j] = f2bu(Wsym[c*128 + r]);
        } else {                               // WnsT[128][128]
            int j = i - 191488; int r = j >> 7, c = j & 127;
            WnsT[j] = f2bu(Wns[c*128 + r]);
        }
    } else if (b < 1580) {                     // NB
        int i = (b - 812)*256 + tid;
        float4 v = ((const float4*)node_ext)[i];
        st_bf16x4(&NB[(size_t)i*4], v);
    } else if (b < 3628) {                     // EB
        for (int i = (b - 1580)*256 + tid; i < NEDGE_*64/4; i += 2048*256) {
            float4 v = ((const float4*)edge_ebd)[i];
            st_bf16x4(&EB[(size_t)i*4], v);
        }
    } else if (b < 4652) {                     // count n2e
        int e = (b - 3628)*256 + tid;
        atomicAdd(&cnt[n2e[e]], 1);
    } else {                                   // count eij2a
        int a = (b - 4652)*256 + tid;
        atomicAdd(&cnt2[eij2a[a]], 1);
    }
}

// ---------------------------------------------------------------------------
// L2: block 0 = node scan; 1..256 = scan2a; 257..320 = nconst; 321..384 = nconstA.
// ---------------------------------------------------------------------------
__global__ __launch_bounds__(256) void k_scan_misc(
    const int* __restrict__ cnt, int* __restrict__ off, int* __restrict__ cursor,
    const int* __restrict__ cnt2, int* __restrict__ bsum,
    const u16* __restrict__ NB, const u16* __restrict__ WTe,
    const u16* __restrict__ WTaN,
    float* __restrict__ nconst, float* __restrict__ nconstA)
{
    __shared__ __align__(16) u16 sN[64][136];
    int* wa = (int*)&sN[0][0];
    const int b = blockIdx.x, t = threadIdx.x;

    if (b == 0) {
        int v[16]; int s = 0;
        #pragma unroll
        for (int k = 0; k < 16; ++k) { v[k] = s; s += cnt[16*t + k]; }
        wa[t] = s;
        __syncthreads();
        for (int d = 1; d < 256; d <<= 1) {
            int x = wa[t];
            int y = (t >= d) ? wa[t-d] : 0;
            __syncthreads();
            wa[t] = x + y;
            __syncthreads();
        }
        int excl = (t == 0) ? 0 : wa[t-1];
        #pragma unroll
        for (int k = 0; k < 16; ++k) {
            off[16*t + k]    = excl + v[k];
            cursor[16*t + k] = excl + v[k];
        }
        if (t == 255) off[4096] = excl + s;
    } else if (b <= 256) {
        int bb = b - 1;
        int4 v = ((const int4*)cnt2)[bb*256 + t];
        wa[t] = v.x + v.y + v.z + v.w;
        __syncthreads();
        for (int d = 128; d > 0; d >>= 1) {
            if (t < d) wa[t] += wa[t+d];
            __syncthreads();
        }
        if (t == 0) bsum[bb] = wa[0];
    } else if (b <= 320) {
        const int e0 = (b - 257) * 64;
        #pragma unroll
        for (int f = t; f < 1024; f += 256) {
            int r = f >> 4, c = f & 15;
            *(uint4*)&sN[r][8*c] = ((const uint4*)&NB[(size_t)(e0 + r)*128])[c];
        }
        __syncthreads();
        const int w = t >> 6, l = t & 63;
        const int lr = l & 15, hq = l >> 4, lk = hq * 8;
        f32x4 acc[4][3] = {};
        #pragma unroll
        for (int kk = 0; kk < 4; ++kk) {
            bf16x8 a[4], bb[3];
            #pragma unroll
            for (int m = 0; m < 4; ++m)
                a[m] = *(const bf16x8*)&sN[16*m + lr][kk*32 + lk];
            #pragma unroll
            for (int nf = 0; nf < 3; ++nf)
                bb[nf] = *(const bf16x8*)&WTe[(size_t)(48*w + 16*nf + lr)*320 + kk*32 + lk];
            #pragma unroll
            for (int m = 0; m < 4; ++m)
                #pragma unroll
                for (int nf = 0; nf < 3; ++nf)
                    acc[m][nf] = __builtin_amdgcn_mfma_f32_16x16x32_bf16(a[m], bb[nf], acc[m][nf], 0, 0, 0);
        }
        #pragma unroll
        for (int nf = 0; nf < 3; ++nf) {
            int c = 48*w + 16*nf + lr;
            #pragma unroll
            for (int m = 0; m < 4; ++m)
                #pragma unroll
                for (int j = 0; j < 4; ++j) {
                    int r = 16*m + 4*hq + j;
                    nconst[(size_t)(e0 + r)*192 + c] = acc[m][nf][j];
                }
        }
    } else {
        const int n0 = (b - 321) * 64;
        #pragma unroll
        for (int f = t; f < 1024; f += 256) {
            int r = f >> 4, c = f & 15;
            *(uint4*)&sN[r][8*c] = ((const uint4*)&NB[(size_t)(n0 + r)*128])[c];
        }
        __syncthreads();
        const int w = t >> 6, l = t & 63;
        const int lr = l & 15, hq = l >> 4, lk = hq * 8;
        f32x4 acc[6] = {};
        #pragma unroll
        for (int kk = 0; kk < 4; ++kk) {
            bf16x8 a = *(const bf16x8*)&sN[16*w + lr][kk*32 + lk];
            #pragma unroll
            for (int nf = 0; nf < 6; ++nf) {
                bf16x8 bb = *(const bf16x8*)&WTaN[(size_t)(16*nf + lr)*128 + kk*32 + lk];
                acc[nf] = __builtin_amdgcn_mfma_f32_16x16x32_bf16(a, bb, acc[nf], 0, 0, 0);
            }
        }
        #pragma unroll
        for (int nf = 0; nf < 6; ++nf) {
            int c = 16*nf + lr;
            #pragma unroll
            for (int j = 0; j < 4; ++j) {
                int r = 16*w + 4*hq + j;
                nconstA[(size_t)(n0 + r)*96 + c] = acc[nf][j];
            }
        }
    }
}

__global__ void k_scan2b(const int* __restrict__ bsum, int* __restrict__ boff)
{
    __shared__ int wa[256];
    int t = threadIdx.x;
    wa[t] = bsum[t];
    __syncthreads();
    for (int d = 1; d < 256; d <<= 1) {
        int x = wa[t];
        int y = (t >= d) ? wa[t-d] : 0;
        __syncthreads();
        wa[t] = x + y;
        __syncthreads();
    }
    boff[t] = (t == 0) ? 0 : wa[t-1];
}

__global__ void k_scan2c(const int* __restrict__ cnt2, const int* __restrict__ boff,
                         int* __restrict__ off2, int* __restrict__ cursor2)
{
    __shared__ int wa[256];
    int b = blockIdx.x, t = threadIdx.x;
    int4 v = ((const int4*)cnt2)[b*256 + t];
    int s1 = v.x, s2 = s1 + v.y, s3 = s2 + v.z, s4 = s3 + v.w;
    wa[t] = s4;
    __syncthreads();
    for (int d = 1; d < 256; d <<= 1) {
        int x = wa[t];
        int y = (t >= d) ? wa[t-d] : 0;
        __syncthreads();
        wa[t] = x + y;
        __syncthreads();
    }
    int base = boff[b] + ((t == 0) ? 0 : wa[t-1]);
    int i = (b*256 + t)*4;
    off2[i]   = base;      cursor2[i]   = base;
    off2[i+1] = base + s1; cursor2[i+1] = base + s1;
    off2[i+2] = base + s2; cursor2[i+2] = base + s2;
    off2[i+3] = base + s3; cursor2[i+3] = base + s3;
    if (b == 255 && t == 255) off2[NEDGE_] = NANGLE_;
}

// L5: fused fills. [0,1024) edge csr; [1024,2624) angle csr2 (sorted list).
__global__ void k_fill2(const int* __restrict__ n2e, int* __restrict__ cursor,
                        int* __restrict__ csr,
                        const int* __restrict__ eij2a, int* __restrict__ cursor2,
                        int* __restrict__ csr2)
{
    int b = blockIdx.x;
    if (b < 1024) {
        int e = b*256 + threadIdx.x;
        int pos = atomicAdd(&cursor[n2e[e]], 1);
        csr[pos] = e;
    } else {
        int a = (b - 1024)*256 + threadIdx.x;
        int pos = atomicAdd(&cursor2[eij2a[a]], 1);
        csr2[pos] = a;
    }
}

// ---------------------------------------------------------------------------
// Flat edge GEMM over CSR-ordered tiles + fused segmented h2g2.
// (round-11 proven form) + XCD-aware bijective block swizzle.
// ---------------------------------------------------------------------------
__global__ __launch_bounds__(256, 4) void k_edge_flat(
    const u16* __restrict__ NB, const u16* __restrict__ EB,
    const float* __restrict__ h2, const float* __restrict__ sw,
    const int* __restrict__ n2e, const int* __restrict__ n_ext2e,
    const int* __restrict__ csr,
    const u16* __restrict__ WTe, const float* __restrict__ nconst,
    const float* __restrict__ bne, const float* __restrict__ bes,
    float* __restrict__ msg,
    float* __restrict__ h2g2_e, float* __restrict__ h2g2_n,
    u16* __restrict__ eselfO)
{
    __shared__ __align__(16) u16 sA[64][200];
    __shared__ float sH[4][576];
    __shared__ int   s_eid[64];
    __shared__ int   s_node[64];
    __shared__ int   s_g[64];
    __shared__ float s_sw[64];
    __shared__ float s_h2[64][3];
    __shared__ int   s_segstart[65];
    __shared__ int   s_nseg;

    const int tid = threadIdx.x;
    const int w  = tid >> 6, l = tid & 63;
    const int lr = l & 15, hq = l >> 4, lk = hq * 8;
    // XCD-aware bijective swizzle: 4096 blocks, 8 XCDs, 512/chunk
    const int bid = blockIdx.x;
    const int base = ((bid & 7) * 512 + (bid >> 3)) * 64;

    if (tid < 64) {
        int e = csr[base + tid];
        s_eid[tid]  = e;
        s_node[tid] = n2e[e];
        s_g[tid]    = n_ext2e[e];
        s_sw[tid]   = sw[e];
        s_h2[tid][0] = h2[e*3];
        s_h2[tid][1] = h2[e*3+1];
        s_h2[tid][2] = h2[e*3+2];
    }
    __syncthreads();

    if (tid < 64) {
        bool flag = (tid == 0) || (s_node[tid] != s_node[tid-1]);
        unsigned long long mask = __ballot(flag);
        if (flag) {
            int sid = __popcll(mask & ((1ull << tid) - 1ull));
            s_segstart[sid] = tid;
        }
        if (tid == 0) {
            int ns = __popcll(mask);
            s_nseg = ns;
            s_segstart[ns] = 64;
        }
    }

    #pragma unroll
    for (int f = tid; f < 1024; f += 256) {
        int r = f >> 4, c = f & 15;
        *(uint4*)&sA[r][8*c] = ((const uint4*)&NB[(size_t)s_g[r]*128])[c];
    }
    #pragma unroll
    for (int f = tid; f < 512; f += 256) {
        int r = f >> 3, c = f & 7;
        *(uint4*)&sA[r][128 + 8*c] = ((const uint4*)&EB[(size_t)s_eid[r]*64])[c];
    }
    __syncthreads();

    float bias[3];
    int   cful[3];
    #pragma unroll
    for (int nf = 0; nf < 3; ++nf) {
        int c = 48*w + 16*nf + lr;
        cful[nf] = c;
        bias[nf] = (c < 128) ? bne[c] : bes[c-128];
    }

    f32x4 acc[4][3] = {};
    #pragma unroll
    for (int kk = 0; kk < 6; ++kk) {
        bf16x8 a[4], b[3];
        #pragma unroll
        for (int m = 0; m < 4; ++m)
            a[m] = *(const bf16x8*)&sA[16*m + lr][kk*32 + lk];
        #pragma unroll
        for (int nf = 0; nf < 3; ++nf)
            b[nf] = *(const bf16x8*)&WTe[(size_t)cful[nf]*320 + 128 + kk*32 + lk];
        #pragma unroll
        for (int m = 0; m < 4; ++m)
            #pragma unroll
            for (int nf = 0; nf < 3; ++nf)
                acc[m][nf] = __builtin_amdgcn_mfma_f32_16x16x32_bf16(a[m], b[nf], acc[m][nf], 0, 0, 0);
    }

    #pragma unroll
    for (int nf = 0; nf < 3; ++nf) {
        int c = cful[nf];
        if (c < 128) {
            #pragma unroll
            for (int m = 0; m < 4; ++m)
                #pragma unroll
                for (int j = 0; j < 4; ++j) {
                    int r = 16*m + 4*hq + j;
                    float ncv = nconst[(size_t)s_node[r]*192 + c];
                    acc[m][nf][j] = silu_(acc[m][nf][j] + ncv + bias[nf]) * s_sw[r];
                }
        } else {
            int c2 = c - 128;
            #pragma unroll
            for (int m = 0; m < 4; ++m)
                #pragma unroll
                for (int j = 0; j < 4; ++j) {
                    int r = 16*m + 4*hq + j;
                    float ncv = nconst[(size_t)s_node[r]*192 + c];
                    eselfO[(size_t)s_eid[r]*64 + c2] =
                        f2bu(silu_(acc[m][nf][j] + ncv + bias[nf]));
                }
        }
    }

    // ---- segmented msg reduction ----
    const int nseg = s_nseg;
    for (int s = 0; s < nseg; ++s) {
        int rs = s_segstart[s], re = s_segstart[s+1];
        int nd = s_node[rs];
        #pragma unroll
        for (int nf = 0; nf < 3; ++nf) {
            if (cful[nf] >= 128) continue;
            float v = 0.f;
            #pragma unroll
            for (int m = 0; m < 4; ++m)
                #pragma unroll
                for (int j = 0; j < 4; ++j) {
                    int r = 16*m + 4*hq + j;
                    v += (r >= rs && r < re) ? acc[m][nf][j] : 0.f;
                }
            v += __shfl_xor(v, 16);
            v += __shfl_xor(v, 32);
            if (hq == 0) atomicAdd(&msg[(size_t)nd*128 + cful[nf]], v);
        }
    }

    // ---- segmented h2g2 accumulation ----
    for (int s = 0; s < nseg; ++s) {
        int rs = s_segstart[s], re = s_segstart[s+1];
        int nd = s_node[rs];
        int lo = max(16*w, rs), hi = min(16*w + 16, re);
        float hacc[9] = {0.f,0.f,0.f,0.f,0.f,0.f,0.f,0.f,0.f};
        for (int r = lo; r < hi; ++r) {
            float swv = s_sw[r];
            float s0 = s_h2[r][0] * swv;
            float s1 = s_h2[r][1] * swv;
            float s2 = s_h2[r][2] * swv;
            float eb = bu2f(sA[r][128 + l]);
            float n0 = bu2f(sA[r][l]);
            float n1 = bu2f(sA[r][64 + l]);
            hacc[0] = fmaf(s0, eb, hacc[0]);
            hacc[1] = fmaf(s1, eb, hacc[1]);
            hacc[2] = fmaf(s2, eb, hacc[2]);
            hacc[3] = fmaf(s0, n0, hacc[3]);
            hacc[4] = fmaf(s0, n1, hacc[4]);
            hacc[5] = fmaf(s1, n0, hacc[5]);
            hacc[6] = fmaf(s1, n1, hacc[6]);
            hacc[7] = fmaf(s2, n0, hacc[7]);
            hacc[8] = fmaf(s2, n1, hacc[8]);
        }
        #pragma unroll
        for (int q = 0; q < 3; ++q) sH[w][q*64 + l] = hacc[q];
        #pragma unroll
        for (int q = 0; q < 6; ++q) sH[w][192 + q*64 + l] = hacc[3+q];
        __syncthreads();
        for (int i = tid; i < 576; i += 256) {
            float v = sH[0][i] + sH[1][i] + sH[2][i] + sH[3][i];
            if (i < 192) atomicAdd(&h2g2_e[(size_t)nd*192 + i], v);
            else         atomicAdd(&h2g2_n[(size_t)nd*384 + (i - 192)], v);
        }
        __syncthreads();
    }
}

// ---------------------------------------------------------------------------
// Angle GEMM via MFMA, eij-SORTED order + XCD swizzle.
// ---------------------------------------------------------------------------
__global__ __launch_bounds__(256) void k_angle_mfma(
    const u16* __restrict__ EB, const float* __restrict__ angle_ebd,
    const float* __restrict__ a_sw,
    const int* __restrict__ n2a, const int* __restrict__ eij2a,
    const int* __restrict__ eik2a, const int* __restrict__ csr2,
    const u16* __restrict__ WTa2, const float* __restrict__ nconstA,
    const float* __restrict__ b1, const float* __restrict__ bA,
    const float* __restrict__ a_res0,
    u16* __restrict__ ea, float* __restrict__ a_out)
{
    __shared__ __align__(16) u16 sA[32][168];
    __shared__ __align__(16) u16 sEA[32][64];
    __shared__ int s_a[32], s_nd[32], s_ij[32], s_ik[32];
    __shared__ float s_asw[32];
    const int tid = threadIdx.x;
    // XCD swizzle: 12800 blocks, 1600/chunk
    const int bid = blockIdx.x;
    const int p0 = ((bid & 7) * 1600 + (bid >> 3)) * 32;

    if (tid < 32) {
        int a = csr2[p0 + tid];
        s_a[tid]  = a;
        s_nd[tid] = n2a[a];
        s_ij[tid] = eij2a[a];
        s_ik[tid] = eik2a[a];
        s_asw[tid] = a_sw[a];
    }
    __syncthreads();

    {                                                // angle_ebd f32 gather
        int r = tid >> 3, c = tid & 7;
        st_bf16x4(&sA[r][4*c], ((const float4*)angle_ebd)[(size_t)s_a[r]*8 + c]);
    }
    {
        int r = tid >> 3, c = tid & 7;
        *(uint4*)&sA[r][32 + 8*c] = ((const uint4*)&EB[(size_t)s_ik[r]*64])[c];
        *(uint4*)&sA[r][96 + 8*c] = ((const uint4*)&EB[(size_t)s_ij[r]*64])[c];
    }
    __syncthreads();

    const int w = tid >> 6, l = tid & 63;
    const int lr = l & 15, hq = l >> 4, lk = hq * 8;
    const int mrow  = (w & 1) * 16;
    const int nbase = (w >> 1) * 48;

    f32x4 acc[3] = {};
    #pragma unroll
    for (int kk = 0; kk < 5; ++kk) {
        bf16x8 a = *(const bf16x8*)&sA[mrow + lr][kk*32 + lk];
        #pragma unroll
        for (int nf = 0; nf < 3; ++nf) {
            bf16x8 b = *(const bf16x8*)&WTa2[(size_t)(nbase + 16*nf + lr)*160 + kk*32 + lk];
            acc[nf] = __builtin_amdgcn_mfma_f32_16x16x32_bf16(a, b, acc[nf], 0, 0, 0);
        }
    }

    #pragma unroll
    for (int nf = 0; nf < 3; ++nf) {
        int c = nbase + 16*nf + lr;
        if (c < 64) {
            float bb = b1[c];
            #pragma unroll
            for (int j = 0; j < 4; ++j) {
                int r = mrow + 4*hq + j;
                float nca = nconstA[(size_t)s_nd[r]*96 + c];
                sEA[r][c] = f2bu(silu_(acc[nf][j] + nca + bb) * s_asw[r]);
            }
        } else {
            int c2 = c - 64;
            float bb = bA[c2], rr = a_res0[c2];
            #pragma unroll
            for (int j = 0; j < 4; ++j) {
                int r = mrow + 4*hq + j;
                float nca = nconstA[(size_t)s_nd[r]*96 + c];
                a_out[(size_t)s_a[r]*32 + c2] =
                    bu2f(sA[r][c2]) + rr * silu_(acc[nf][j] + nca + bb);
            }
        }
    }
    __syncthreads();

    {                                                // sequential ea store
        int r = tid >> 3, c = tid & 7;
        *(uint4*)&ea[((size_t)(p0 + r))*64 + 8*c] = *(const uint4*)&sEA[r][8*c];
    }
}

// ---------------------------------------------------------------------------
// L8 fused: [0,4096) edgefin; [4096,8192) symc.
// ---------------------------------------------------------------------------
__global__ __launch_bounds__(256) void k_fin(
    const u16* __restrict__ EB, const u16* __restrict__ eselfO,
    const u16* __restrict__ ea, const int* __restrict__ off2,
    const u16* __restrict__ WT2,
    const float* __restrict__ b2_, const float* __restrict__ er0,
    const float* __restrict__ er1,
    float* __restrict__ e_out,
    const float* __restrict__ h2g2_e, const float* __restrict__ h2g2_n,
    u16* __restrict__ symcB)
{
    __shared__ __align__(16) u16 sR[64][72];
    __shared__ __align__(16) u16 sE[64][72];
    __shared__ __align__(16) u16 sB[64][72];
    const int tid = threadIdx.x;
    const int blk = blockIdx.x;

    if (blk < 4096) {
        const int e0 = blk * 64;
        const int w = tid >> 6, l = tid & 63;

        #pragma unroll
        for (int f = tid; f < 512; f += 256) {
            int r = f >> 3, c = f & 7;
            *(uint4*)&sB[r][8*c] = ((const uint4*)&EB[(size_t)(e0 + r)*64])[c];
            *(uint4*)&sE[r][8*c] = ((const uint4*)&eselfO[(size_t)(e0 + r)*64])[c];
        }

        #pragma unroll
        for (int r16 = 0; r16 < 16; ++r16) {
            int r = w*16 + r16;
            int e = e0 + r;
            float s = 0.f;
            int jb = off2[e], je = off2[e+1];
            for (int j = jb; j < je; ++j)
                s += bu2f(ea[(size_t)j*64 + l]);
            sR[r][l] = f2bu(s);
        }
        __syncthreads();

        const int lr = l & 15, hq = l >> 4, lk = hq * 8;
        f32x4 acc[4] = {};
        #pragma unroll
        for (int kk = 0; kk < 2; ++kk) {
            bf16x8 b = *(const bf16x8*)&WT2[(size_t)(16*w + lr)*64 + kk*32 + lk];
            #pragma unroll
            for (int m = 0; m < 4; ++m) {
                bf16x8 a = *(const bf16x8*)&sR[16*m + lr][kk*32 + lk];
                acc[m] = __builtin_amdgcn_mfma_f32_16x16x32_bf16(a, b, acc[m], 0, 0, 0);
            }
        }
        int c = 16*w + lr;
        float bb = b2_[c], r0 = er0[c], r1 = er1[c];
        #pragma unroll
        for (int m = 0; m < 4; ++m)
            #pragma unroll
            for (int j = 0; j < 4; ++j) {
                int r = 16*m + 4*hq + j;
                size_t idx = (size_t)(e0 + r)*64 + c;
                e_out[idx] = bu2f(sB[r][c]) + r0 * bu2f(sE[r][c])
                           + r1 * silu_(acc[m][j] + bb);
            }
    } else {
        const int n = blk - 4096;
        float* he = (float*)&sR[0][0];
        float* hn = he + 192;
        for (int i = tid; i < 192; i += 256) he[i] = h2g2_e[(size_t)n*192 + i];
        for (int i = tid; i < 384; i += 256) hn[i] = h2g2_n[(size_t)n*384 + i];
        __syncthreads();
        const float SCALE = 1.0f / (6.4f * 3.0f);
        for (int i = tid; i < 768; i += 256) {
            float s;
            if (i < 256) {
                int a = i >> 6, j = i & 63;
                s = he[a]*he[j] + he[64+a]*he[64+j] + he[128+a]*he[128+j];
            } else {
                int i2 = i - 256;
                int a = i2 >> 7, j = i2 & 127;
                s = hn[a]*hn[j] + hn[128+a]*hn[128+j] + hn[256+a]*hn[256+j];
            }
            symcB[(size_t)n*768 + i] = f2bu(s * SCALE);
        }
    }
}

// ---------------------------------------------------------------------------
// Node finalize via MFMA.
// ---------------------------------------------------------------------------
__global__ __launch_bounds__(256) void k_node_mfma(
    const u16* __restrict__ symcB, const u16* __restrict__ NB,
    const float* __restrict__ node_ext, const float* __restrict__ msg,
    const u16* __restrict__ WsymT, const u16* __restrict__ WnsT,
    const float* __restrict__ bns, const float* __restrict__ bsym,
    const float* __restrict__ nr0, const float* __restrict__ nr1,
    const float* __restrict__ nr2,
    float* __restrict__ n_out)
{
    __shared__ __align__(16) u16 sA[32][264];
    const int tid = threadIdx.x;
    const int n0 = blockIdx.x * 32;
    const int w = tid >> 6, l = tid & 63;
    const int lr = l & 15, hq = l >> 4, lk = hq * 8;

    f32x4 accY[2][2] = {};
    f32x4 accS[2][2] = {};

    for (int chunk = 0; chunk < 3; ++chunk) {
        __syncthreads();
        #pragma unroll
        for (int f = tid; f < 1024; f += 256) {
            int r = f >> 5, c = f & 31;
            *(uint4*)&sA[r][8*c] =
                ((const uint4*)&symcB[(size_t)(n0 + r)*768 + chunk*256])[c];
        }
        __syncthreads();
        #pragma unroll
        for (int kk = 0; kk < 8; ++kk) {
            bf16x8 a[2], b[2];
            #pragma unroll
            for (int m = 0; m < 2; ++m)
                a[m] = *(const bf16x8*)&sA[16*m + lr][kk*32 + lk];
            #pragma unroll
            for (int nf = 0; nf < 2; ++nf)
                b[nf] = *(const bf16x8*)&WsymT[(size_t)(32*w + 16*nf + lr)*768
                                               + chunk*256 + kk*32 + lk];
            #pragma unroll
            for (int m = 0; m < 2; ++m)
                #pragma unroll
                for (int nf = 0; nf < 2; ++nf)
                    accY[m][nf] = __builtin_amdgcn_mfma_f32_16x16x32_bf16(a[m], b[nf], accY[m][nf], 0, 0, 0);
        }
    }

    __syncthreads();
    #pragma unroll
    for (int f = tid; f < 512; f += 256) {
        int r = f >> 4, c = f & 15;
        *(uint4*)&sA[r][8*c] = ((const uint4*)&NB[(size_t)(n0 + r)*128])[c];
    }
    __syncthreads();
    #pragma unroll
    for (int kk = 0; kk < 4; ++kk) {
        bf16x8 a[2], b[2];
        #pragma unroll
        for (int m = 0; m < 2; ++m)
            a[m] = *(const bf16x8*)&sA[16*m + lr][kk*32 + lk];
        #pragma unroll
        for (int nf = 0; nf < 2; ++nf)
            b[nf] = *(const bf16x8*)&WnsT[(size_t)(32*w + 16*nf + lr)*128 + kk*32 + lk];
        #pragma unroll
        for (int m = 0; m < 2; ++m)
            #pragma unroll
            for (int nf = 0; nf < 2; ++nf)
                accS[m][nf] = __builtin_amdgcn_mfma_f32_16x16x32_bf16(a[m], b[nf], accS[m][nf], 0, 0, 0);
    }

    #pragma unroll
    for (int nf = 0; nf < 2; ++nf) {
        int c = 32*w + 16*nf + lr;
        float bS = bns[c], bY = bsym[c];
        float r0 = nr0[c], r1 = nr1[c], r2 = nr2[c];
        #pragma unroll
        for (int m = 0; m < 2; ++m)
            #pragma unroll
            for (int j = 0; j < 4; ++j) {
                int r = 16*m + 4*hq + j;
                size_t idx = (size_t)(n0 + r)*128 + c;
                float self_ = silu_(accS[m][nf][j] + bS);
                float sym_  = silu_(accY[m][nf][j] + bY);
                n_out[idx] = node_ext[idx] + r0*self_ + r1*sym_
                           + r2 * msg[idx] * (1.0f / 6.4f);
            }
    }
}

// ---------------------------------------------------------------------------
extern "C" void kernel_launch(void* const* d_in, const int* in_sizes, int n_in,
                              void* d_out, int out_size, void* d_ws, size_t ws_size,
                              hipStream_t stream)
{
    const float* node_ext  = (const float*)d_in[0];
    const float* edge_ebd  = (const float*)d_in[1];
    const float* h2        = (const float*)d_in[2];
    const float* angle_ebd = (const float*)d_in[3];
    const float* sw        = (const float*)d_in[6];
    const float* a_sw      = (const float*)d_in[9];
    const int*  edge_index  = (const int*)d_in[10];
    const int*  angle_index = (const int*)d_in[11];
    const int* n2e     = edge_index;
    const int* n_ext2e = edge_index + NEDGE_;
    const int* n2a     = angle_index;
    const int* eij2a   = angle_index + NANGLE_;
    const int* eik2a   = angle_index + 2*NANGLE_;

    const float* Wns  = (const float*)d_in[12];
    const float* bns  = (const float*)d_in[13];
    const float* Wsym = (const float*)d_in[14];
    const float* bsym = (const float*)d_in[15];
    const float* Wne  = (const float*)d_in[16];
    const float* bne  = (const float*)d_in[17];
    const float* Wes  = (const float*)d_in[18];
    const float* bes  = (const float*)d_in[19];
    const float* W1   = (const float*)d_in[20];
    const float* b1   = (const float*)d_in[21];
    const float* W2   = (const float*)d_in[22];
    const float* b2_  = (const float*)d_in[23];
    const float* WA   = (const float*)d_in[24];
    const float* bA   = (const float*)d_in[25];
    const float* nr0  = (const float*)d_in[26];
    const float* nr1  = (const float*)d_in[27];
    const float* nr2  = (const float*)d_in[28];
    const float* er0  = (const float*)d_in[29];
    const float* er1  = (const float*)d_in[30];
    const float* ar0  = (const float*)d_in[31];

    // workspace layout
    char* wsp = (char*)d_ws;
    u16*   ea      = (u16*)wsp;    wsp += (size_t)NANGLE_ * 64 * 2;
    u16*   EB      = (u16*)wsp;    wsp += (size_t)NEDGE_ * 64 * 2;
    u16*   NB      = (u16*)wsp;    wsp += (size_t)NALL_ * 128 * 2;
    u16*   eselfO  = (u16*)wsp;    wsp += (size_t)NEDGE_ * 64 * 2;
    u16*   symcB   = (u16*)wsp;    wsp += (size_t)NLOC_ * 768 * 2;
    // zeroed region: [cnt | cnt2 | msg | h2g2_e | h2g2_n]
    int*   cnt     = (int*)wsp;    wsp += 4096 * 4;
    int*   cnt2    = (int*)wsp;    wsp += (size_t)NEDGE_ * 4;
    float* msg     = (float*)wsp;  wsp += (size_t)NLOC_ * 128 * 4;
    float* h2g2_e  = (float*)wsp;  wsp += (size_t)NLOC_ * 192 * 4;
    float* h2g2_n  = (float*)wsp;  wsp += (size_t)NLOC_ * 384 * 4;
    size_t zero_bytes = 4096*4 + (size_t)NEDGE_*4 + (size_t)NLOC_*128*4
                      + (size_t)NLOC_*192*4 + (size_t)NLOC_*384*4;
    int*   off     = (int*)wsp;    wsp += 4104 * 4;
    int*   cursor  = (int*)wsp;    wsp += 4096 * 4;
    int*   csr     = (int*)wsp;    wsp += (size_t)NEDGE_ * 4;
    int*   off2    = (int*)wsp;    wsp += ((size_t)NEDGE_ + 16) * 4;
    int*   cursor2 = (int*)wsp;    wsp += (size_t)NEDGE_ * 4;
    int*   bsum    = (int*)wsp;    wsp += 256 * 4;
    int*   boff    = (int*)wsp;    wsp += 256 * 4;
    int*   csr2    = (int*)wsp;    wsp += (size_t)NANGLE_ * 4;
    float* nconst  = (float*)wsp;  wsp += (size_t)NLOC_ * 192 * 4;
    float* nconstA = (float*)wsp;  wsp += (size_t)NLOC_ * 96 * 4;
    u16*   WTe     = (u16*)wsp;    wsp += 192 * 320 * 2;
    u16*   WTa2    = (u16*)wsp;    wsp += 96 * 160 * 2;
    u16*   WTaN    = (u16*)wsp;    wsp += 96 * 128 * 2;
    u16*   WT2     = (u16*)wsp;    wsp += 64 * 64 * 2;
    u16*   WsymT   = (u16*)wsp;    wsp += 128 * 768 * 2;
    u16*   WnsT    = (u16*)wsp;    wsp += 128 * 128 * 2;

    hipMemsetAsync(cnt, 0, zero_bytes, stream);

    float* n_out = (float*)d_out;
    float* e_out = n_out + (size_t)NLOC_ * 128;
    float* a_out = e_out + (size_t)NEDGE_ * 64;

    k_mega_prep <<<6252, 256, 0, stream>>>(Wne, Wes, W1, WA, W2, Wsym, Wns,
                                           node_ext, edge_ebd,
                                           n2e, eij2a,
                                           WTe, WTa2, WTaN, WT2, WsymT, WnsT,
                                           NB, EB, cnt, cnt2);
    k_scan_misc <<<385, 256, 0, stream>>>(cnt, off, cursor, cnt2, bsum,
                                          NB, WTe, WTaN, nconst, nconstA);
    k_scan2b <<<1, 256, 0, stream>>>(bsum, boff);
    k_scan2c <<<256, 256, 0, stream>>>(cnt2, boff, off2, cursor2);
    k_fill2  <<<2624, 256, 0, stream>>>(n2e, cursor, csr, eij2a, cursor2, csr2);

    k_edge_flat <<<NEDGE_/64, 256, 0, stream>>>(NB, EB, h2, sw, n2e, n_ext2e, csr,
                                                WTe, nconst, bne, bes,
                                                msg, h2g2_e, h2g2_n, eselfO);
    k_angle_mfma <<<NANGLE_/32, 256, 0, stream>>>(EB, angle_ebd, a_sw,
                                                  n2a, eij2a, eik2a, csr2,
                                                  WTa2, nconstA, b1, bA, ar0,
                                                  ea, a_out);
    k_fin <<<8192, 256, 0, stream>>>(EB, eselfO, ea, off2, WT2, b2_, er0, er1,
                                     e_out, h2g2_e, h2g2_n, symcB);
    k_node_mfma <<<NLOC_/32, 256, 0, stream>>>(symcB, NB, node_ext, msg,
                                               WsymT, WnsT, bns, bsym,
                                               nr0, nr1, nr2, n_out);
}

// Round 16
// 422.079 us; speedup vs baseline: 1.2538x; 1.0035x over previous
//
#include <hip/hip_runtime.h>
#include <hip/hip_bf16.h>

#define NLOC_   4096
#define NALL_   6144
#define NEDGE_  262144
#define NANGLE_ 409600

typedef __bf16 bf16x8 __attribute__((ext_vector_type(8)));
typedef float  f32x4  __attribute__((ext_vector_type(4)));
typedef unsigned short u16;

__device__ __forceinline__ float silu_(float x){ return x / (1.0f + __expf(-x)); }

__device__ __forceinline__ u16 f2bu(float f){
    union { float f; unsigned u; } v; v.f = f;
    unsigned r = v.u + 0x7fffu + ((v.u >> 16) & 1u);
    return (u16)(r >> 16);
}
__device__ __forceinline__ float bu2f(u16 b){
    union { unsigned u; float f; } v; v.u = ((unsigned)b) << 16; return v.f;
}
__device__ __forceinline__ void st_bf16x4(u16* dst, float4 v){
    unsigned lo = (unsigned)f2bu(v.x) | ((unsigned)f2bu(v.y) << 16);
    unsigned hi = (unsigned)f2bu(v.z) | ((unsigned)f2bu(v.w) << 16);
    *reinterpret_cast<uint2*>(dst) = make_uint2(lo, hi);
}

// ---------------------------------------------------------------------------
// L1 mega-prep: weight transposes + bf16 tables + CSR counts, block-ranged.
// ---------------------------------------------------------------------------
__global__ __launch_bounds__(256) void k_mega_prep(
    const float* __restrict__ Wne, const float* __restrict__ Wes,
    const float* __restrict__ W1,  const float* __restrict__ WA,
    const float* __restrict__ W2,  const float* __restrict__ Wsym,
    const float* __restrict__ Wns,
    const float* __restrict__ node_ext, const float* __restrict__ edge_ebd,
    const int* __restrict__ n2e, const int* __restrict__ eij2a,
    u16* __restrict__ WTe, u16* __restrict__ WTa2, u16* __restrict__ WTaN,
    u16* __restrict__ WT2, u16* __restrict__ WsymT, u16* __restrict__ WnsT,
    u16* __restrict__ NB, u16* __restrict__ EB,
    int* __restrict__ cnt, int* __restrict__ cnt2)
{
    const int b = blockIdx.x, tid = threadIdx.x;
    if (b < 812) {
        int i = b*256 + tid;
        if (i < 61440) {                       // WTe[192][320]
            int r = i/320, c = i - r*320;
            WTe[i] = f2bu(r < 128 ? Wne[c*128 + r] : Wes[c*64 + (r-128)]);
        } else if (i < 76800) {                // WTa2[96][160]
            int j = i - 61440; int r = j/160, c2 = j - r*160;
            int k = (c2 < 32) ? c2 : c2 + 128;
            WTa2[j] = f2bu(r < 64 ? W1[k*64 + r] : WA[k*32 + (r-64)]);
        } else if (i < 89088) {                // WTaN[96][128]
            int j = i - 76800; int r = j >> 7, c2 = j & 127;
            int k = c2 + 32;
            WTaN[j] = f2bu(r < 64 ? W1[k*64 + r] : WA[k*32 + (r-64)]);
        } else if (i < 93184) {                // WT2[64][64]
            int j = i - 89088; int r = j >> 6, c = j & 63;
            WT2[j] = f2bu(W2[c*64 + r]);
        } else if (i < 191488) {               // WsymT[128][768]
            int j = i - 93184; int r = j/768, c = j - r*768;
            WsymT[j] = f2bu(Wsym[c*128 + r]);
        } else {                               // WnsT[128][128]
            int j = i - 191488; int r = j >> 7, c = j & 127;
            WnsT[j] = f2bu(Wns[c*128 + r]);
        }
    } else if (b < 1580) {                     // NB
        int i = (b - 812)*256 + tid;
        float4 v = ((const float4*)node_ext)[i];
        st_bf16x4(&NB[(size_t)i*4], v);
    } else if (b < 3628) {                     // EB
        for (int i = (b - 1580)*256 + tid; i < NEDGE_*64/4; i += 2048*256) {
            float4 v = ((const float4*)edge_ebd)[i];
            st_bf16x4(&EB[(size_t)i*4], v);
        }
    } else if (b < 4652) {                     // count n2e
        int e = (b - 3628)*256 + tid;
        atomicAdd(&cnt[n2e[e]], 1);
    } else {                                   // count eij2a
        int a = (b - 4652)*256 + tid;
        atomicAdd(&cnt2[eij2a[a]], 1);
    }
}

// ---------------------------------------------------------------------------
// L2: block 0 = node scan; 1..256 = scan2a; 257..320 = nconst; 321..384 = nconstA.
// ---------------------------------------------------------------------------
__global__ __launch_bounds__(256) void k_scan_misc(
    const int* __restrict__ cnt, int* __restrict__ off, int* __restrict__ cursor,
    const int* __restrict__ cnt2, int* __restrict__ bsum,
    const u16* __restrict__ NB, const u16* __restrict__ WTe,
    const u16* __restrict__ WTaN,
    float* __restrict__ nconst, float* __restrict__ nconstA)
{
    __shared__ __align__(16) u16 sN[64][136];
    int* wa = (int*)&sN[0][0];
    const int b = blockIdx.x, t = threadIdx.x;

    if (b == 0) {
        int v[16]; int s = 0;
        #pragma unroll
        for (int k = 0; k < 16; ++k) { v[k] = s; s += cnt[16*t + k]; }
        wa[t] = s;
        __syncthreads();
        for (int d = 1; d < 256; d <<= 1) {
            int x = wa[t];
            int y = (t >= d) ? wa[t-d] : 0;
            __syncthreads();
            wa[t] = x + y;
            __syncthreads();
        }
        int excl = (t == 0) ? 0 : wa[t-1];
        #pragma unroll
        for (int k = 0; k < 16; ++k) {
            off[16*t + k]    = excl + v[k];
            cursor[16*t + k] = excl + v[k];
        }
        if (t == 255) off[4096] = excl + s;
    } else if (b <= 256) {
        int bb = b - 1;
        int4 v = ((const int4*)cnt2)[bb*256 + t];
        wa[t] = v.x + v.y + v.z + v.w;
        __syncthreads();
        for (int d = 128; d > 0; d >>= 1) {
            if (t < d) wa[t] += wa[t+d];
            __syncthreads();
        }
        if (t == 0) bsum[bb] = wa[0];
    } else if (b <= 320) {
        const int e0 = (b - 257) * 64;
        #pragma unroll
        for (int f = t; f < 1024; f += 256) {
            int r = f >> 4, c = f & 15;
            *(uint4*)&sN[r][8*c] = ((const uint4*)&NB[(size_t)(e0 + r)*128])[c];
        }
        __syncthreads();
        const int w = t >> 6, l = t & 63;
        const int lr = l & 15, hq = l >> 4, lk = hq * 8;
        f32x4 acc[4][3] = {};
        #pragma unroll
        for (int kk = 0; kk < 4; ++kk) {
            bf16x8 a[4], bb[3];
            #pragma unroll
            for (int m = 0; m < 4; ++m)
                a[m] = *(const bf16x8*)&sN[16*m + lr][kk*32 + lk];
            #pragma unroll
            for (int nf = 0; nf < 3; ++nf)
                bb[nf] = *(const bf16x8*)&WTe[(size_t)(48*w + 16*nf + lr)*320 + kk*32 + lk];
            #pragma unroll
            for (int m = 0; m < 4; ++m)
                #pragma unroll
                for (int nf = 0; nf < 3; ++nf)
                    acc[m][nf] = __builtin_amdgcn_mfma_f32_16x16x32_bf16(a[m], bb[nf], acc[m][nf], 0, 0, 0);
        }
        #pragma unroll
        for (int nf = 0; nf < 3; ++nf) {
            int c = 48*w + 16*nf + lr;
            #pragma unroll
            for (int m = 0; m < 4; ++m)
                #pragma unroll
                for (int j = 0; j < 4; ++j) {
                    int r = 16*m + 4*hq + j;
                    nconst[(size_t)(e0 + r)*192 + c] = acc[m][nf][j];
                }
        }
    } else {
        const int n0 = (b - 321) * 64;
        #pragma unroll
        for (int f = t; f < 1024; f += 256) {
            int r = f >> 4, c = f & 15;
            *(uint4*)&sN[r][8*c] = ((const uint4*)&NB[(size_t)(n0 + r)*128])[c];
        }
        __syncthreads();
        const int w = t >> 6, l = t & 63;
        const int lr = l & 15, hq = l >> 4, lk = hq * 8;
        f32x4 acc[6] = {};
        #pragma unroll
        for (int kk = 0; kk < 4; ++kk) {
            bf16x8 a = *(const bf16x8*)&sN[16*w + lr][kk*32 + lk];
            #pragma unroll
            for (int nf = 0; nf < 6; ++nf) {
                bf16x8 bb = *(const bf16x8*)&WTaN[(size_t)(16*nf + lr)*128 + kk*32 + lk];
                acc[nf] = __builtin_amdgcn_mfma_f32_16x16x32_bf16(a, bb, acc[nf], 0, 0, 0);
            }
        }
        #pragma unroll
        for (int nf = 0; nf < 6; ++nf) {
            int c = 16*nf + lr;
            #pragma unroll
            for (int j = 0; j < 4; ++j) {
                int r = 16*w + 4*hq + j;
                nconstA[(size_t)(n0 + r)*96 + c] = acc[nf][j];
            }
        }
    }
}

__global__ void k_scan2b(const int* __restrict__ bsum, int* __restrict__ boff)
{
    __shared__ int wa[256];
    int t = threadIdx.x;
    wa[t] = bsum[t];
    __syncthreads();
    for (int d = 1; d < 256; d <<= 1) {
        int x = wa[t];
        int y = (t >= d) ? wa[t-d] : 0;
        __syncthreads();
        wa[t] = x + y;
        __syncthreads();
    }
    boff[t] = (t == 0) ? 0 : wa[t-1];
}

__global__ void k_scan2c(const int* __restrict__ cnt2, const int* __restrict__ boff,
                         int* __restrict__ off2, int* __restrict__ cursor2)
{
    __shared__ int wa[256];
    int b = blockIdx.x, t = threadIdx.x;
    int4 v = ((const int4*)cnt2)[b*256 + t];
    int s1 = v.x, s2 = s1 + v.y, s3 = s2 + v.z, s4 = s3 + v.w;
    wa[t] = s4;
    __syncthreads();
    for (int d = 1; d < 256; d <<= 1) {
        int x = wa[t];
        int y = (t >= d) ? wa[t-d] : 0;
        __syncthreads();
        wa[t] = x + y;
        __syncthreads();
    }
    int base = boff[b] + ((t == 0) ? 0 : wa[t-1]);
    int i = (b*256 + t)*4;
    off2[i]   = base;      cursor2[i]   = base;
    off2[i+1] = base + s1; cursor2[i+1] = base + s1;
    off2[i+2] = base + s2; cursor2[i+2] = base + s2;
    off2[i+3] = base + s3; cursor2[i+3] = base + s3;
    if (b == 255 && t == 255) off2[NEDGE_] = NANGLE_;
}

// L5: fused fills. [0,1024) edge csr; [1024,2624) angle csr2 (sorted list).
__global__ void k_fill2(const int* __restrict__ n2e, int* __restrict__ cursor,
                        int* __restrict__ csr,
                        const int* __restrict__ eij2a, int* __restrict__ cursor2,
                        int* __restrict__ csr2)
{
    int b = blockIdx.x;
    if (b < 1024) {
        int e = b*256 + threadIdx.x;
        int pos = atomicAdd(&cursor[n2e[e]], 1);
        csr[pos] = e;
    } else {
        int a = (b - 1024)*256 + threadIdx.x;
        int pos = atomicAdd(&cursor2[eij2a[a]], 1);
        csr2[pos] = a;
    }
}

// ---------------------------------------------------------------------------
// Flat edge GEMM over CSR-ordered tiles + fused segmented h2g2.
// (round-11 proven form) + XCD-aware bijective block swizzle (kept: helped).
// ---------------------------------------------------------------------------
__global__ __launch_bounds__(256, 4) void k_edge_flat(
    const u16* __restrict__ NB, const u16* __restrict__ EB,
    const float* __restrict__ h2, const float* __restrict__ sw,
    const int* __restrict__ n2e, const int* __restrict__ n_ext2e,
    const int* __restrict__ csr,
    const u16* __restrict__ WTe, const float* __restrict__ nconst,
    const float* __restrict__ bne, const float* __restrict__ bes,
    float* __restrict__ msg,
    float* __restrict__ h2g2_e, float* __restrict__ h2g2_n,
    u16* __restrict__ eselfO)
{
    __shared__ __align__(16) u16 sA[64][200];
    __shared__ float sH[4][576];
    __shared__ int   s_eid[64];
    __shared__ int   s_node[64];
    __shared__ int   s_g[64];
    __shared__ float s_sw[64];
    __shared__ float s_h2[64][3];
    __shared__ int   s_segstart[65];
    __shared__ int   s_nseg;

    const int tid = threadIdx.x;
    const int w  = tid >> 6, l = tid & 63;
    const int lr = l & 15, hq = l >> 4, lk = hq * 8;
    // XCD-aware bijective swizzle: 4096 blocks, 8 XCDs, 512/chunk
    const int bid = blockIdx.x;
    const int base = ((bid & 7) * 512 + (bid >> 3)) * 64;

    if (tid < 64) {
        int e = csr[base + tid];
        s_eid[tid]  = e;
        s_node[tid] = n2e[e];
        s_g[tid]    = n_ext2e[e];
        s_sw[tid]   = sw[e];
        s_h2[tid][0] = h2[e*3];
        s_h2[tid][1] = h2[e*3+1];
        s_h2[tid][2] = h2[e*3+2];
    }
    __syncthreads();

    if (tid < 64) {
        bool flag = (tid == 0) || (s_node[tid] != s_node[tid-1]);
        unsigned long long mask = __ballot(flag);
        if (flag) {
            int sid = __popcll(mask & ((1ull << tid) - 1ull));
            s_segstart[sid] = tid;
        }
        if (tid == 0) {
            int ns = __popcll(mask);
            s_nseg = ns;
            s_segstart[ns] = 64;
        }
    }

    #pragma unroll
    for (int f = tid; f < 1024; f += 256) {
        int r = f >> 4, c = f & 15;
        *(uint4*)&sA[r][8*c] = ((const uint4*)&NB[(size_t)s_g[r]*128])[c];
    }
    #pragma unroll
    for (int f = tid; f < 512; f += 256) {
        int r = f >> 3, c = f & 7;
        *(uint4*)&sA[r][128 + 8*c] = ((const uint4*)&EB[(size_t)s_eid[r]*64])[c];
    }
    __syncthreads();

    float bias[3];
    int   cful[3];
    #pragma unroll
    for (int nf = 0; nf < 3; ++nf) {
        int c = 48*w + 16*nf + lr;
        cful[nf] = c;
        bias[nf] = (c < 128) ? bne[c] : bes[c-128];
    }

    f32x4 acc[4][3] = {};
    #pragma unroll
    for (int kk = 0; kk < 6; ++kk) {
        bf16x8 a[4], b[3];
        #pragma unroll
        for (int m = 0; m < 4; ++m)
            a[m] = *(const bf16x8*)&sA[16*m + lr][kk*32 + lk];
        #pragma unroll
        for (int nf = 0; nf < 3; ++nf)
            b[nf] = *(const bf16x8*)&WTe[(size_t)cful[nf]*320 + 128 + kk*32 + lk];
        #pragma unroll
        for (int m = 0; m < 4; ++m)
            #pragma unroll
            for (int nf = 0; nf < 3; ++nf)
                acc[m][nf] = __builtin_amdgcn_mfma_f32_16x16x32_bf16(a[m], b[nf], acc[m][nf], 0, 0, 0);
    }

    #pragma unroll
    for (int nf = 0; nf < 3; ++nf) {
        int c = cful[nf];
        if (c < 128) {
            #pragma unroll
            for (int m = 0; m < 4; ++m)
                #pragma unroll
                for (int j = 0; j < 4; ++j) {
                    int r = 16*m + 4*hq + j;
                    float ncv = nconst[(size_t)s_node[r]*192 + c];
                    acc[m][nf][j] = silu_(acc[m][nf][j] + ncv + bias[nf]) * s_sw[r];
                }
        } else {
            int c2 = c - 128;
            #pragma unroll
            for (int m = 0; m < 4; ++m)
                #pragma unroll
                for (int j = 0; j < 4; ++j) {
                    int r = 16*m + 4*hq + j;
                    float ncv = nconst[(size_t)s_node[r]*192 + c];
                    eselfO[(size_t)s_eid[r]*64 + c2] =
                        f2bu(silu_(acc[m][nf][j] + ncv + bias[nf]));
                }
        }
    }

    // ---- segmented msg reduction ----
    const int nseg = s_nseg;
    for (int s = 0; s < nseg; ++s) {
        int rs = s_segstart[s], re = s_segstart[s+1];
        int nd = s_node[rs];
        #pragma unroll
        for (int nf = 0; nf < 3; ++nf) {
            if (cful[nf] >= 128) continue;
            float v = 0.f;
            #pragma unroll
            for (int m = 0; m < 4; ++m)
                #pragma unroll
                for (int j = 0; j < 4; ++j) {
                    int r = 16*m + 4*hq + j;
                    v += (r >= rs && r < re) ? acc[m][nf][j] : 0.f;
                }
            v += __shfl_xor(v, 16);
            v += __shfl_xor(v, 32);
            if (hq == 0) atomicAdd(&msg[(size_t)nd*128 + cful[nf]], v);
        }
    }

    // ---- segmented h2g2 accumulation ----
    for (int s = 0; s < nseg; ++s) {
        int rs = s_segstart[s], re = s_segstart[s+1];
        int nd = s_node[rs];
        int lo = max(16*w, rs), hi = min(16*w + 16, re);
        float hacc[9] = {0.f,0.f,0.f,0.f,0.f,0.f,0.f,0.f,0.f};
        for (int r = lo; r < hi; ++r) {
            float swv = s_sw[r];
            float s0 = s_h2[r][0] * swv;
            float s1 = s_h2[r][1] * swv;
            float s2 = s_h2[r][2] * swv;
            float eb = bu2f(sA[r][128 + l]);
            float n0 = bu2f(sA[r][l]);
            float n1 = bu2f(sA[r][64 + l]);
            hacc[0] = fmaf(s0, eb, hacc[0]);
            hacc[1] = fmaf(s1, eb, hacc[1]);
            hacc[2] = fmaf(s2, eb, hacc[2]);
            hacc[3] = fmaf(s0, n0, hacc[3]);
            hacc[4] = fmaf(s0, n1, hacc[4]);
            hacc[5] = fmaf(s1, n0, hacc[5]);
            hacc[6] = fmaf(s1, n1, hacc[6]);
            hacc[7] = fmaf(s2, n0, hacc[7]);
            hacc[8] = fmaf(s2, n1, hacc[8]);
        }
        #pragma unroll
        for (int q = 0; q < 3; ++q) sH[w][q*64 + l] = hacc[q];
        #pragma unroll
        for (int q = 0; q < 6; ++q) sH[w][192 + q*64 + l] = hacc[3+q];
        __syncthreads();
        for (int i = tid; i < 576; i += 256) {
            float v = sH[0][i] + sH[1][i] + sH[2][i] + sH[3][i];
            if (i < 192) atomicAdd(&h2g2_e[(size_t)nd*192 + i], v);
            else         atomicAdd(&h2g2_n[(size_t)nd*384 + (i - 192)], v);
        }
        __syncthreads();
    }
}

// ---------------------------------------------------------------------------
// Angle GEMM via MFMA, eij-SORTED order (NO swizzle — swizzle hurt locality).
// ---------------------------------------------------------------------------
__global__ __launch_bounds__(256) void k_angle_mfma(
    const u16* __restrict__ EB, const float* __restrict__ angle_ebd,
    const float* __restrict__ a_sw,
    const int* __restrict__ n2a, const int* __restrict__ eij2a,
    const int* __restrict__ eik2a, const int* __restrict__ csr2,
    const u16* __restrict__ WTa2, const float* __restrict__ nconstA,
    const float* __restrict__ b1, const float* __restrict__ bA,
    const float* __restrict__ a_res0,
    u16* __restrict__ ea, float* __restrict__ a_out)
{
    __shared__ __align__(16) u16 sA[32][168];
    __shared__ __align__(16) u16 sEA[32][64];
    __shared__ int s_a[32], s_nd[32], s_ij[32], s_ik[32];
    __shared__ float s_asw[32];
    const int tid = threadIdx.x;
    const int p0 = blockIdx.x * 32;

    if (tid < 32) {
        int a = csr2[p0 + tid];
        s_a[tid]  = a;
        s_nd[tid] = n2a[a];
        s_ij[tid] = eij2a[a];
        s_ik[tid] = eik2a[a];
        s_asw[tid] = a_sw[a];
    }
    __syncthreads();

    {                                                // angle_ebd f32 gather
        int r = tid >> 3, c = tid & 7;
        st_bf16x4(&sA[r][4*c], ((const float4*)angle_ebd)[(size_t)s_a[r]*8 + c]);
    }
    {
        int r = tid >> 3, c = tid & 7;
        *(uint4*)&sA[r][32 + 8*c] = ((const uint4*)&EB[(size_t)s_ik[r]*64])[c];
        *(uint4*)&sA[r][96 + 8*c] = ((const uint4*)&EB[(size_t)s_ij[r]*64])[c];
    }
    __syncthreads();

    const int w = tid >> 6, l = tid & 63;
    const int lr = l & 15, hq = l >> 4, lk = hq * 8;
    const int mrow  = (w & 1) * 16;
    const int nbase = (w >> 1) * 48;

    f32x4 acc[3] = {};
    #pragma unroll
    for (int kk = 0; kk < 5; ++kk) {
        bf16x8 a = *(const bf16x8*)&sA[mrow + lr][kk*32 + lk];
        #pragma unroll
        for (int nf = 0; nf < 3; ++nf) {
            bf16x8 b = *(const bf16x8*)&WTa2[(size_t)(nbase + 16*nf + lr)*160 + kk*32 + lk];
            acc[nf] = __builtin_amdgcn_mfma_f32_16x16x32_bf16(a, b, acc[nf], 0, 0, 0);
        }
    }

    #pragma unroll
    for (int nf = 0; nf < 3; ++nf) {
        int c = nbase + 16*nf + lr;
        if (c < 64) {
            float bb = b1[c];
            #pragma unroll
            for (int j = 0; j < 4; ++j) {
                int r = mrow + 4*hq + j;
                float nca = nconstA[(size_t)s_nd[r]*96 + c];
                sEA[r][c] = f2bu(silu_(acc[nf][j] + nca + bb) * s_asw[r]);
            }
        } else {
            int c2 = c - 64;
            float bb = bA[c2], rr = a_res0[c2];
            #pragma unroll
            for (int j = 0; j < 4; ++j) {
                int r = mrow + 4*hq + j;
                float nca = nconstA[(size_t)s_nd[r]*96 + c];
                a_out[(size_t)s_a[r]*32 + c2] =
                    bu2f(sA[r][c2]) + rr * silu_(acc[nf][j] + nca + bb);
            }
        }
    }
    __syncthreads();

    {                                                // sequential ea store
        int r = tid >> 3, c = tid & 7;
        *(uint4*)&ea[((size_t)(p0 + r))*64 + 8*c] = *(const uint4*)&sEA[r][8*c];
    }
}

// ---------------------------------------------------------------------------
// L8 fused: [0,4096) edgefin; [4096,8192) symc.
// ---------------------------------------------------------------------------
__global__ __launch_bounds__(256) void k_fin(
    const u16* __restrict__ EB, const u16* __restrict__ eselfO,
    const u16* __restrict__ ea, const int* __restrict__ off2,
    const u16* __restrict__ WT2,
    const float* __restrict__ b2_, const float* __restrict__ er0,
    const float* __restrict__ er1,
    float* __restrict__ e_out,
    const float* __restrict__ h2g2_e, const float* __restrict__ h2g2_n,
    u16* __restrict__ symcB)
{
    __shared__ __align__(16) u16 sR[64][72];
    __shared__ __align__(16) u16 sE[64][72];
    __shared__ __align__(16) u16 sB[64][72];
    const int tid = threadIdx.x;
    const int blk = blockIdx.x;

    if (blk < 4096) {
        const int e0 = blk * 64;
        const int w = tid >> 6, l = tid & 63;

        #pragma unroll
        for (int f = tid; f < 512; f += 256) {
            int r = f >> 3, c = f & 7;
            *(uint4*)&sB[r][8*c] = ((const uint4*)&EB[(size_t)(e0 + r)*64])[c];
            *(uint4*)&sE[r][8*c] = ((const uint4*)&eselfO[(size_t)(e0 + r)*64])[c];
        }

        #pragma unroll
        for (int r16 = 0; r16 < 16; ++r16) {
            int r = w*16 + r16;
            int e = e0 + r;
            float s = 0.f;
            int jb = off2[e], je = off2[e+1];
            for (int j = jb; j < je; ++j)
                s += bu2f(ea[(size_t)j*64 + l]);
            sR[r][l] = f2bu(s);
        }
        __syncthreads();

        const int lr = l & 15, hq = l >> 4, lk = hq * 8;
        f32x4 acc[4] = {};
        #pragma unroll
        for (int kk = 0; kk < 2; ++kk) {
            bf16x8 b = *(const bf16x8*)&WT2[(size_t)(16*w + lr)*64 + kk*32 + lk];
            #pragma unroll
            for (int m = 0; m < 4; ++m) {
                bf16x8 a = *(const bf16x8*)&sR[16*m + lr][kk*32 + lk];
                acc[m] = __builtin_amdgcn_mfma_f32_16x16x32_bf16(a, b, acc[m], 0, 0, 0);
            }
        }
        int c = 16*w + lr;
        float bb = b2_[c], r0 = er0[c], r1 = er1[c];
        #pragma unroll
        for (int m = 0; m < 4; ++m)
            #pragma unroll
            for (int j = 0; j < 4; ++j) {
                int r = 16*m + 4*hq + j;
                size_t idx = (size_t)(e0 + r)*64 + c;
                e_out[idx] = bu2f(sB[r][c]) + r0 * bu2f(sE[r][c])
                           + r1 * silu_(acc[m][j] + bb);
            }
    } else {
        const int n = blk - 4096;
        float* he = (float*)&sR[0][0];
        float* hn = he + 192;
        for (int i = tid; i < 192; i += 256) he[i] = h2g2_e[(size_t)n*192 + i];
        for (int i = tid; i < 384; i += 256) hn[i] = h2g2_n[(size_t)n*384 + i];
        __syncthreads();
        const float SCALE = 1.0f / (6.4f * 3.0f);
        for (int i = tid; i < 768; i += 256) {
            float s;
            if (i < 256) {
                int a = i >> 6, j = i & 63;
                s = he[a]*he[j] + he[64+a]*he[64+j] + he[128+a]*he[128+j];
            } else {
                int i2 = i - 256;
                int a = i2 >> 7, j = i2 & 127;
                s = hn[a]*hn[j] + hn[128+a]*hn[128+j] + hn[256+a]*hn[256+j];
            }
            symcB[(size_t)n*768 + i] = f2bu(s * SCALE);
        }
    }
}

// ---------------------------------------------------------------------------
// Node finalize via MFMA.
// ---------------------------------------------------------------------------
__global__ __launch_bounds__(256) void k_node_mfma(
    const u16* __restrict__ symcB, const u16* __restrict__ NB,
    const float* __restrict__ node_ext, const float* __restrict__ msg,
    const u16* __restrict__ WsymT, const u16* __restrict__ WnsT,
    const float* __restrict__ bns, const float* __restrict__ bsym,
    const float* __restrict__ nr0, const float* __restrict__ nr1,
    const float* __restrict__ nr2,
    float* __restrict__ n_out)
{
    __shared__ __align__(16) u16 sA[32][264];
    const int tid = threadIdx.x;
    const int n0 = blockIdx.x * 32;
    const int w = tid >> 6, l = tid & 63;
    const int lr = l & 15, hq = l >> 4, lk = hq * 8;

    f32x4 accY[2][2] = {};
    f32x4 accS[2][2] = {};

    for (int chunk = 0; chunk < 3; ++chunk) {
        __syncthreads();
        #pragma unroll
        for (int f = tid; f < 1024; f += 256) {
            int r = f >> 5, c = f & 31;
            *(uint4*)&sA[r][8*c] =
                ((const uint4*)&symcB[(size_t)(n0 + r)*768 + chunk*256])[c];
        }
        __syncthreads();
        #pragma unroll
        for (int kk = 0; kk < 8; ++kk) {
            bf16x8 a[2], b[2];
            #pragma unroll
            for (int m = 0; m < 2; ++m)
                a[m] = *(const bf16x8*)&sA[16*m + lr][kk*32 + lk];
            #pragma unroll
            for (int nf = 0; nf < 2; ++nf)
                b[nf] = *(const bf16x8*)&WsymT[(size_t)(32*w + 16*nf + lr)*768
                                               + chunk*256 + kk*32 + lk];
            #pragma unroll
            for (int m = 0; m < 2; ++m)
                #pragma unroll
                for (int nf = 0; nf < 2; ++nf)
                    accY[m][nf] = __builtin_amdgcn_mfma_f32_16x16x32_bf16(a[m], b[nf], accY[m][nf], 0, 0, 0);
        }
    }

    __syncthreads();
    #pragma unroll
    for (int f = tid; f < 512; f += 256) {
        int r = f >> 4, c = f & 15;
        *(uint4*)&sA[r][8*c] = ((const uint4*)&NB[(size_t)(n0 + r)*128])[c];
    }
    __syncthreads();
    #pragma unroll
    for (int kk = 0; kk < 4; ++kk) {
        bf16x8 a[2], b[2];
        #pragma unroll
        for (int m = 0; m < 2; ++m)
            a[m] = *(const bf16x8*)&sA[16*m + lr][kk*32 + lk];
        #pragma unroll
        for (int nf = 0; nf < 2; ++nf)
            b[nf] = *(const bf16x8*)&WnsT[(size_t)(32*w + 16*nf + lr)*128 + kk*32 + lk];
        #pragma unroll
        for (int m = 0; m < 2; ++m)
            #pragma unroll
            for (int nf = 0; nf < 2; ++nf)
                accS[m][nf] = __builtin_amdgcn_mfma_f32_16x16x32_bf16(a[m], b[nf], accS[m][nf], 0, 0, 0);
    }

    #pragma unroll
    for (int nf = 0; nf < 2; ++nf) {
        int c = 32*w + 16*nf + lr;
        float bS = bns[c], bY = bsym[c];
        float r0 = nr0[c], r1 = nr1[c], r2 = nr2[c];
        #pragma unroll
        for (int m = 0; m < 2; ++m)
            #pragma unroll
            for (int j = 0; j < 4; ++j) {
                int r = 16*m + 4*hq + j;
                size_t idx = (size_t)(n0 + r)*128 + c;
                float self_ = silu_(accS[m][nf][j] + bS);
                float sym_  = silu_(accY[m][nf][j] + bY);
                n_out[idx] = node_ext[idx] + r0*self_ + r1*sym_
                           + r2 * msg[idx] * (1.0f / 6.4f);
            }
    }
}

// ---------------------------------------------------------------------------
extern "C" void kernel_launch(void* const* d_in, const int* in_sizes, int n_in,
                              void* d_out, int out_size, void* d_ws, size_t ws_size,
                              hipStream_t stream)
{
    const float* node_ext  = (const float*)d_in[0];
    const float* edge_ebd  = (const float*)d_in[1];
    const float* h2        = (const float*)d_in[2];
    const float* angle_ebd = (const float*)d_in[3];
    const float* sw        = (const float*)d_in[6];
    const float* a_sw      = (const float*)d_in[9];
    const int*  edge_index  = (const int*)d_in[10];
    const int*  angle_index = (const int*)d_in[11];
    const int* n2e     = edge_index;
    const int* n_ext2e = edge_index + NEDGE_;
    const int* n2a     = angle_index;
    const int* eij2a   = angle_index + NANGLE_;
    const int* eik2a   = angle_index + 2*NANGLE_;

    const float* Wns  = (const float*)d_in[12];
    const float* bns  = (const float*)d_in[13];
    const float* Wsym = (const float*)d_in[14];
    const float* bsym = (const float*)d_in[15];
    const float* Wne  = (const float*)d_in[16];
    const float* bne  = (const float*)d_in[17];
    const float* Wes  = (const float*)d_in[18];
    const float* bes  = (const float*)d_in[19];
    const float* W1   = (const float*)d_in[20];
    const float* b1   = (const float*)d_in[21];
    const float* W2   = (const float*)d_in[22];
    const float* b2_  = (const float*)d_in[23];
    const float* WA   = (const float*)d_in[24];
    const float* bA   = (const float*)d_in[25];
    const float* nr0  = (const float*)d_in[26];
    const float* nr1  = (const float*)d_in[27];
    const float* nr2  = (const float*)d_in[28];
    const float* er0  = (const float*)d_in[29];
    const float* er1  = (const float*)d_in[30];
    const float* ar0  = (const float*)d_in[31];

    // workspace layout
    char* wsp = (char*)d_ws;
    u16*   ea      = (u16*)wsp;    wsp += (size_t)NANGLE_ * 64 * 2;
    u16*   EB      = (u16*)wsp;    wsp += (size_t)NEDGE_ * 64 * 2;
    u16*   NB      = (u16*)wsp;    wsp += (size_t)NALL_ * 128 * 2;
    u16*   eselfO  = (u16*)wsp;    wsp += (size_t)NEDGE_ * 64 * 2;
    u16*   symcB   = (u16*)wsp;    wsp += (size_t)NLOC_ * 768 * 2;
    // zeroed region: [cnt | cnt2 | msg | h2g2_e | h2g2_n]
    int*   cnt     = (int*)wsp;    wsp += 4096 * 4;
    int*   cnt2    = (int*)wsp;    wsp += (size_t)NEDGE_ * 4;
    float* msg     = (float*)wsp;  wsp += (size_t)NLOC_ * 128 * 4;
    float* h2g2_e  = (float*)wsp;  wsp += (size_t)NLOC_ * 192 * 4;
    float* h2g2_n  = (float*)wsp;  wsp += (size_t)NLOC_ * 384 * 4;
    size_t zero_bytes = 4096*4 + (size_t)NEDGE_*4 + (size_t)NLOC_*128*4
                      + (size_t)NLOC_*192*4 + (size_t)NLOC_*384*4;
    int*   off     = (int*)wsp;    wsp += 4104 * 4;
    int*   cursor  = (int*)wsp;    wsp += 4096 * 4;
    int*   csr     = (int*)wsp;    wsp += (size_t)NEDGE_ * 4;
    int*   off2    = (int*)wsp;    wsp += ((size_t)NEDGE_ + 16) * 4;
    int*   cursor2 = (int*)wsp;    wsp += (size_t)NEDGE_ * 4;
    int*   bsum    = (int*)wsp;    wsp += 256 * 4;
    int*   boff    = (int*)wsp;    wsp += 256 * 4;
    int*   csr2    = (int*)wsp;    wsp += (size_t)NANGLE_ * 4;
    float* nconst  = (float*)wsp;  wsp += (size_t)NLOC_ * 192 * 4;
    float* nconstA = (float*)wsp;  wsp += (size_t)NLOC_ * 96 * 4;
    u16*   WTe     = (u16*)wsp;    wsp += 192 * 320 * 2;
    u16*   WTa2    = (u16*)wsp;    wsp += 96 * 160 * 2;
    u16*   WTaN    = (u16*)wsp;    wsp += 96 * 128 * 2;
    u16*   WT2     = (u16*)wsp;    wsp += 64 * 64 * 2;
    u16*   WsymT   = (u16*)wsp;    wsp += 128 * 768 * 2;
    u16*   WnsT    = (u16*)wsp;    wsp += 128 * 128 * 2;

    hipMemsetAsync(cnt, 0, zero_bytes, stream);

    float* n_out = (float*)d_out;
    float* e_out = n_out + (size_t)NLOC_ * 128;
    float* a_out = e_out + (size_t)NEDGE_ * 64;

    k_mega_prep <<<6252, 256, 0, stream>>>(Wne, Wes, W1, WA, W2, Wsym, Wns,
                                           node_ext, edge_ebd,
                                           n2e, eij2a,
                                           WTe, WTa2, WTaN, WT2, WsymT, WnsT,
                                           NB, EB, cnt, cnt2);
    k_scan_misc <<<385, 256, 0, stream>>>(cnt, off, cursor, cnt2, bsum,
                                          NB, WTe, WTaN, nconst, nconstA);
    k_scan2b <<<1, 256, 0, stream>>>(bsum, boff);
    k_scan2c <<<256, 256, 0, stream>>>(cnt2, boff, off2, cursor2);
    k_fill2  <<<2624, 256, 0, stream>>>(n2e, cursor, csr, eij2a, cursor2, csr2);

    k_edge_flat <<<NEDGE_/64, 256, 0, stream>>>(NB, EB, h2, sw, n2e, n_ext2e, csr,
                                                WTe, nconst, bne, bes,
                                                msg, h2g2_e, h2g2_n, eselfO);
    k_angle_mfma <<<NANGLE_/32, 256, 0, stream>>>(EB, angle_ebd, a_sw,
                                                  n2a, eij2a, eik2a, csr2,
                                                  WTa2, nconstA, b1, bA, ar0,
                                                  ea, a_out);
    k_fin <<<8192, 256, 0, stream>>>(EB, eselfO, ea, off2, WT2, b2_, er0, er1,
                                     e_out, h2g2_e, h2g2_n, symcB);
    k_node_mfma <<<NLOC_/32, 256, 0, stream>>>(symcB, NB, node_ext, msg,
                                               WsymT, WnsT, bns, bsym,
                                               nr0, nr1, nr2, n_out);
}